// Round 6
// baseline (2122.808 us; speedup 1.0000x reference)
//
#include <hip/hip_runtime.h>

typedef short s8v __attribute__((ext_vector_type(8)));
typedef float f4v __attribute__((ext_vector_type(4)));

#define MFMA16(a,b,c) __builtin_amdgcn_mfma_f32_16x16x32_bf16((a),(b),(c),0,0,0)

#define N_NODES 4096
#define N_EDGE  131072
#define ATT_SCALE 0.17677669529663687f   // 1/sqrt(32)
#define NGC2     -1.5957691216057308f    // -2*sqrt(2/pi)

// fast path (hot kernel): round-half-up, 2 VALU
__device__ __forceinline__ unsigned short f2bf(float f) {
  union { float f; unsigned u; } v; v.f = f;
  return (unsigned short)((v.u + 0x8000u) >> 16);
}
// precise path (one-time prep): RNE
__device__ __forceinline__ unsigned short f2bf_rne(float f) {
  union { float f; unsigned u; } v; v.f = f;
  unsigned r = v.u + 0x7fffu + ((v.u >> 16) & 1u);
  return (unsigned short)(r >> 16);
}
__device__ __forceinline__ float bf2f(short s) {
  union { unsigned u; float f; } v;
  v.u = ((unsigned)(unsigned short)s) << 16;
  return v.f;
}
__device__ __forceinline__ int iclamp(int v, int lo, int hi) {
  return v < lo ? lo : (v > hi ? hi : v);
}

// ---------------- prep kernels ----------------

__global__ void k_tr(const float* __restrict__ src, short* __restrict__ dst,
                     int L, int K, int N) {
  int idx = blockIdx.x * 256 + threadIdx.x;
  int tot = L * K * N;
  if (idx >= tot) return;
  int l = idx / (K * N);
  int r = idx - l * (K * N);
  int k = r / N;
  int n = r - k * N;
  dst[l * K * N + n * K + k] = (short)f2bf_rne(src[idx]);
}

__global__ void k_tabs(const float* __restrict__ cart, const float* __restrict__ cemb,
                       const float* __restrict__ nemb, const float* __restrict__ comp,
                       float* __restrict__ tabs) {
  int idx = blockIdx.x * 256 + threadIdx.x;
  if (idx >= 1408) return;
  float s = 0.f;
  if (idx < 384) {
    int i = idx >> 7, d = idx & 127;
    for (int j = 0; j < 128; ++j) s += cart[i * 128 + j] * comp[j * 128 + d];
  } else if (idx < 896) {
    int i2 = idx - 384; int sp = i2 >> 7, d = i2 & 127;
    for (int j = 0; j < 128; ++j) s += cemb[sp * 128 + j] * comp[(128 + j) * 128 + d];
  } else {
    int i2 = idx - 896; int sp = i2 >> 7, d = i2 & 127;
    for (int j = 0; j < 128; ++j) s += nemb[sp * 128 + j] * comp[(256 + j) * 128 + d];
  }
  tabs[idx] = s;
}

__global__ void k_rm(const float* __restrict__ ev, const int* __restrict__ centers,
                     const int* __restrict__ nef2, float* __restrict__ rm) {
  int e = blockIdx.x * 256 + threadIdx.x;
  if (e >= N_EDGE) return;
  float x = ev[e*3], y = ev[e*3+1], z = ev[e*3+2];
  float r = sqrtf(x*x + y*y + z*z);
  float rad;
  if (r < 3.0f)      rad = 1.0f;
  else if (r < 5.0f) rad = 0.5f * (cosf(3.14159265358979f * (r - 3.0f) * 0.5f) + 1.0f);
  else               rad = 0.0f;
  int c  = iclamp(centers[e], 0, N_NODES - 1);
  int rk = iclamp(nef2[e], 0, 63);
  rm[c * 64 + rk] = rad;
}

__global__ __launch_bounds__(256) void k_enc(
    const float* __restrict__ ev, const int* __restrict__ nef,
    const int* __restrict__ centers, const int* __restrict__ neighbors,
    const int* __restrict__ species, const float* __restrict__ tabs,
    short* __restrict__ feat) {
  int n = blockIdx.x, t = threadIdx.x, j = t >> 2, qq = t & 3;
  int e = iclamp(nef[n * 64 + j], 0, N_EDGE - 1);
  float e0 = ev[e*3], e1 = ev[e*3+1], e2 = ev[e*3+2];
  int nc = iclamp(centers[e],   0, N_NODES - 1);
  int nn = iclamp(neighbors[e], 0, N_NODES - 1);
  int sc = iclamp(species[nc], 0, 3), sn = iclamp(species[nn], 0, 3);
  const float* m0 = tabs + qq*32;
  const float* m1 = tabs + 128 + qq*32;
  const float* m2 = tabs + 256 + qq*32;
  const float* tc = tabs + 384 + sc*128 + qq*32;
  const float* tn = tabs + 896 + sn*128 + qq*32;
  short* o = feat + ((size_t)(n*64 + j))*128 + qq*32;
  #pragma unroll
  for (int i = 0; i < 32; i += 2) {
    float a = e0*m0[i]   + e1*m1[i]   + e2*m2[i]   + tc[i]   + tn[i];
    float b = e0*m0[i+1] + e1*m1[i+1] + e2*m2[i+1] + tc[i+1] + tn[i+1];
    *(unsigned*)(o + i) = (unsigned)f2bf_rne(a) | ((unsigned)f2bf_rne(b) << 16);
  }
}

// ---------------- fused transformer (2 layers), static 52KB LDS ----------------
// block = one node; 4 waves partition columns. Residual x in f32 regs,
// MFMA C-layout: row = mt*16+quad*4+reg, col = wid*32+nt*16+l4.
// LDS: hb (17408) | kb (17408) | vtb (18432, red 2048 aliased at its base).
// Register policy (rounds 2-5 post-mortem): ANY waves-per-eu/launch_bounds cap
// makes the allocator split the arch+acc budget ~evenly, capping arch VGPRs
// below the ~200 peak live set -> scratch spills (160MB..1.2GB HBM traffic).
// Plain __launch_bounds__(256) gives a 512-reg budget: zero spills, 2 blocks/CU.

__device__ __forceinline__ void ln_sub(float (&xr)[4][2][4],
                                       const float* __restrict__ gw, const float* __restrict__ gb,
                                       float* red, short* hb, int wid, int quad, int l4) {
  #pragma unroll
  for (int mt = 0; mt < 4; ++mt)
    #pragma unroll
    for (int reg = 0; reg < 4; ++reg) {
      float a = xr[mt][0][reg] + xr[mt][1][reg];
      float s = xr[mt][0][reg]*xr[mt][0][reg] + xr[mt][1][reg]*xr[mt][1][reg];
      #pragma unroll
      for (int m = 1; m < 16; m <<= 1) { a += __shfl_xor(a, m); s += __shfl_xor(s, m); }
      if (l4 == 0) {
        int r = mt*16 + quad*4 + reg;
        red[(wid*64 + r)*2]     = a;
        red[(wid*64 + r)*2 + 1] = s;
      }
    }
  __syncthreads();
  int tid = threadIdx.x;
  if (tid < 64) {
    float a = 0.f, s = 0.f;
    #pragma unroll
    for (int w = 0; w < 4; ++w) { a += red[(w*64 + tid)*2]; s += red[(w*64 + tid)*2 + 1]; }
    float mean = a * (1.f/128.f);
    float var  = s * (1.f/128.f) - mean*mean;
    red[tid*2]     = mean;
    red[tid*2 + 1] = rsqrtf(var + 1e-5f);
  }
  __syncthreads();
  float gv[2], bv[2];
  #pragma unroll
  for (int nt = 0; nt < 2; ++nt) { int c = wid*32 + nt*16 + l4; gv[nt] = gw[c]; bv[nt] = gb[c]; }
  #pragma unroll
  for (int mt = 0; mt < 4; ++mt)
    #pragma unroll
    for (int reg = 0; reg < 4; ++reg) {
      int r = mt*16 + quad*4 + reg;
      float mean = red[r*2], inv = red[r*2 + 1];
      #pragma unroll
      for (int nt = 0; nt < 2; ++nt) {
        float h = (xr[mt][nt][reg] - mean) * inv * gv[nt] + bv[nt];
        hb[r*136 + wid*32 + nt*16 + l4] = (short)f2bf(h);
      }
    }
  __syncthreads();
}

__global__ __launch_bounds__(256) void k_tf(
    short* __restrict__ x, const float* __restrict__ rm,
    const float* __restrict__ lnw1, const float* __restrict__ lnb1,
    const short* __restrict__ qkvT, const float* __restrict__ qkvb,
    const short* __restrict__ outT, const float* __restrict__ outb,
    const float* __restrict__ lnw2, const float* __restrict__ lnb2,
    const short* __restrict__ m1T, const float* __restrict__ m1b,
    const short* __restrict__ m2T, const float* __restrict__ m2b) {
  __shared__ __align__(16) char smem[53248];
  short* hb  = (short*)smem;              // 17408 B: LN-out / q / attn-out
  short* kb  = (short*)(smem + 17408);    // 17408 B: k ; P-scratch (own cols); MLP G0
  short* vtb = (short*)(smem + 34816);    // 18432 B: V^T [feat128][key stride 72]; MLP G1
  float* red = (float*)(smem + 34816);    // 2048 B aliased at vtb base (LN phases only)

  const int tid = threadIdx.x;
  const int wid = tid >> 6;
  const int lane = tid & 63;
  const int l4 = lane & 15;
  const int quad = lane >> 4;
  const int n = blockIdx.x;

  float rv[4];
  #pragma unroll
  for (int n2 = 0; n2 < 4; ++n2) rv[n2] = rm[n*64 + n2*16 + l4];

  short* xg = x + (size_t)n * 64 * 128;
  float xr[4][2][4];
  #pragma unroll
  for (int mt = 0; mt < 4; ++mt)
    #pragma unroll
    for (int nt = 0; nt < 2; ++nt)
      #pragma unroll
      for (int reg = 0; reg < 4; ++reg)
        xr[mt][nt][reg] = bf2f(xg[(mt*16 + quad*4 + reg)*128 + wid*32 + nt*16 + l4]);

  for (int l = 0; l < 2; ++l) {
    const float* g1    = lnw1 + l*128;   const float* bb1   = lnb1 + l*128;
    const short* qkvTl = qkvT + l*49152; const float* qkvbl = qkvb + l*384;
    const short* outTl = outT + l*16384; const float* outbl = outb + l*128;
    const float* g2    = lnw2 + l*128;   const float* bb2   = lnb2 + l*128;
    const short* m1Tl  = m1T + l*65536;  const float* m1bl  = m1b + l*512;
    const short* m2Tl  = m2T + l*65536;  const float* m2bl  = m2b + l*128;

    // guard red(=vtb) writes vs previous layer's MLP G1 reads
    __syncthreads();

    ln_sub(xr, g1, bb1, red, hb, wid, quad, l4);   // -> hb, trailing barrier

    // ---- QKV: waves partition 384 cols (96 each); q overwrites hb ----
    {
      s8v af[4][4];
      #pragma unroll
      for (int mt = 0; mt < 4; ++mt)
        #pragma unroll
        for (int k0 = 0; k0 < 4; ++k0)
          af[mt][k0] = *(const s8v*)(hb + (mt*16 + l4)*136 + k0*32 + quad*8);
      __syncthreads();   // everyone has h in regs; hb reusable as q

      #pragma unroll 2
      for (int j = 0; j < 6; ++j) {
        int col = wid*96 + j*16 + l4;
        s8v bf[4];
        #pragma unroll
        for (int k0 = 0; k0 < 4; ++k0)
          bf[k0] = *(const s8v*)(qkvTl + col*128 + k0*32 + quad*8);
        float bias = qkvbl[col];
        f4v acc[4];
        #pragma unroll
        for (int mt = 0; mt < 4; ++mt) { f4v bb = {bias,bias,bias,bias}; acc[mt] = bb; }
        #pragma unroll
        for (int k0 = 0; k0 < 4; ++k0)
          #pragma unroll
          for (int mt = 0; mt < 4; ++mt)
            acc[mt] = MFMA16(af[mt][k0], bf[k0], acc[mt]);
        if (col < 128) {
          #pragma unroll
          for (int mt = 0; mt < 4; ++mt)
            #pragma unroll
            for (int reg = 0; reg < 4; ++reg)
              hb[(mt*16 + quad*4 + reg)*136 + col] = (short)f2bf(acc[mt][reg] * ATT_SCALE);
        } else if (col < 256) {
          int c = col - 128;
          #pragma unroll
          for (int mt = 0; mt < 4; ++mt)
            #pragma unroll
            for (int reg = 0; reg < 4; ++reg)
              kb[(mt*16 + quad*4 + reg)*136 + c] = (short)f2bf(acc[mt][reg]);
        } else {
          int c = col - 256;
          #pragma unroll
          for (int mt = 0; mt < 4; ++mt)
            #pragma unroll
            for (int reg = 0; reg < 4; ++reg)
              vtb[c*72 + (mt*16 + quad*4 + reg)] = (short)f2bf(acc[mt][reg]);
        }
      }
    }
    __syncthreads();

    // ---- attention: wave = head; zero internal barriers.
    // Wave h only touches hb/kb columns [h*32, h*32+32) after loading its frags.
    {
      const int h = wid;
      s8v aq[4], bk[4];
      #pragma unroll
      for (int mt = 0; mt < 4; ++mt)
        aq[mt] = *(const s8v*)(hb + (mt*16 + l4)*136 + h*32 + quad*8);
      #pragma unroll
      for (int n2 = 0; n2 < 4; ++n2)
        bk[n2] = *(const s8v*)(kb + (n2*16 + l4)*136 + h*32 + quad*8);
      f4v S[4][4];
      #pragma unroll
      for (int mt = 0; mt < 4; ++mt)
        #pragma unroll
        for (int n2 = 0; n2 < 4; ++n2) {
          f4v zz = {0.f,0.f,0.f,0.f};
          S[mt][n2] = MFMA16(aq[mt], bk[n2], zz);
        }

      #pragma unroll
      for (int mt = 0; mt < 4; ++mt)
        #pragma unroll
        for (int reg = 0; reg < 4; ++reg) {
          float mx = fmaxf(fmaxf(S[mt][0][reg], S[mt][1][reg]),
                           fmaxf(S[mt][2][reg], S[mt][3][reg]));
          mx = fmaxf(mx, __shfl_xor(mx, 1));
          mx = fmaxf(mx, __shfl_xor(mx, 2));
          mx = fmaxf(mx, __shfl_xor(mx, 4));
          mx = fmaxf(mx, __shfl_xor(mx, 8));
          float E = 0.f, W = 0.f;
          #pragma unroll
          for (int n2 = 0; n2 < 4; ++n2) {
            float e = __expf(S[mt][n2][reg] - mx);
            E += e; W += e * rv[n2];
            S[mt][n2][reg] = e * rv[n2];
          }
          E += __shfl_xor(E, 1); E += __shfl_xor(E, 2);
          E += __shfl_xor(E, 4); E += __shfl_xor(E, 8);
          W += __shfl_xor(W, 1); W += __shfl_xor(W, 2);
          W += __shfl_xor(W, 4); W += __shfl_xor(W, 8);
          float inv = __builtin_amdgcn_rcpf(W + 1e-9f * E);
          #pragma unroll
          for (int n2 = 0; n2 < 4; ++n2) S[mt][n2][reg] *= inv;
        }

      // PV in 32-key chunks; P transposed through own kb columns
      f4v o[4][2];
      #pragma unroll
      for (int mt = 0; mt < 4; ++mt)
        #pragma unroll
        for (int nt = 0; nt < 2; ++nt) { f4v zz = {0.f,0.f,0.f,0.f}; o[mt][nt] = zz; }
      for (int c = 0; c < 2; ++c) {
        #pragma unroll
        for (int mt = 0; mt < 4; ++mt)
          #pragma unroll
          for (int n2 = 0; n2 < 2; ++n2)
            #pragma unroll
            for (int reg = 0; reg < 4; ++reg)
              kb[(mt*16 + quad*4 + reg)*136 + h*32 + n2*16 + l4] =
                  (short)f2bf(S[mt][2*c + n2][reg]);
        s8v ap[4];
        #pragma unroll
        for (int mt = 0; mt < 4; ++mt)
          ap[mt] = *(const s8v*)(kb + (mt*16 + l4)*136 + h*32 + quad*8);
        #pragma unroll
        for (int nt = 0; nt < 2; ++nt) {
          s8v bv = *(const s8v*)(vtb + (h*32 + nt*16 + l4)*72 + c*32 + quad*8);
          #pragma unroll
          for (int mt = 0; mt < 4; ++mt)
            o[mt][nt] = MFMA16(ap[mt], bv, o[mt][nt]);
        }
      }
      #pragma unroll
      for (int mt = 0; mt < 4; ++mt)
        #pragma unroll
        for (int nt = 0; nt < 2; ++nt)
          #pragma unroll
          for (int reg = 0; reg < 4; ++reg)
            hb[(mt*16 + quad*4 + reg)*136 + h*32 + nt*16 + l4] = (short)f2bf(o[mt][nt][reg]);
    }
    __syncthreads();

    // ---- output proj + residual ----
    {
      s8v ao[4][4];
      #pragma unroll
      for (int mt = 0; mt < 4; ++mt)
        #pragma unroll
        for (int k0 = 0; k0 < 4; ++k0)
          ao[mt][k0] = *(const s8v*)(hb + (mt*16 + l4)*136 + k0*32 + quad*8);
      #pragma unroll
      for (int nt = 0; nt < 2; ++nt) {
        int c = wid*32 + nt*16 + l4;
        s8v bo[4];
        #pragma unroll
        for (int k0 = 0; k0 < 4; ++k0)
          bo[k0] = *(const s8v*)(outTl + c*128 + k0*32 + quad*8);
        float bias = outbl[c];
        #pragma unroll
        for (int mt = 0; mt < 4; ++mt) {
          f4v a2 = {xr[mt][nt][0] + bias, xr[mt][nt][1] + bias,
                    xr[mt][nt][2] + bias, xr[mt][nt][3] + bias};
          #pragma unroll
          for (int k0 = 0; k0 < 4; ++k0)
            a2 = MFMA16(ao[mt][k0], bo[k0], a2);
          #pragma unroll
          for (int reg = 0; reg < 4; ++reg)
            xr[mt][nt][reg] = a2[reg];
        }
      }
    }

    ln_sub(xr, g2, bb2, red, hb, wid, quad, l4);   // LN2 -> hb

    // ---- MLP: gelu double-buffered in kb (G0) / vtb (G1); 1 barrier per chunk ----
    {
      s8v afm[4][4];
      #pragma unroll
      for (int mt = 0; mt < 4; ++mt)
        #pragma unroll
        for (int k0 = 0; k0 < 4; ++k0)
          afm[mt][k0] = *(const s8v*)(hb + (mt*16 + l4)*136 + k0*32 + quad*8);

      for (int cc = 0; cc < 4; ++cc) {
        short* G = (cc & 1) ? vtb : kb;
        #pragma unroll
        for (int nt = 0; nt < 2; ++nt) {
          int jc = cc*128 + wid*32 + nt*16 + l4;
          s8v bm[4];
          #pragma unroll
          for (int k0 = 0; k0 < 4; ++k0)
            bm[k0] = *(const s8v*)(m1Tl + jc*128 + k0*32 + quad*8);
          float bias = m1bl[jc];
          #pragma unroll
          for (int mt = 0; mt < 4; ++mt) {
            f4v a2 = {bias, bias, bias, bias};
            #pragma unroll
            for (int k0 = 0; k0 < 4; ++k0)
              a2 = MFMA16(afm[mt][k0], bm[k0], a2);
            #pragma unroll
            for (int reg = 0; reg < 4; ++reg) {
              // gelu(v) = v * sigmoid(2*sqrt(2/pi)*(v + 0.044715 v^3))
              float v = a2[reg];
              float t = v * v;
              float u = fmaf(0.044715f, t, 1.0f);
              float w = v * u;
              float e = __expf(NGC2 * w);
              float gl = v * __builtin_amdgcn_rcpf(e + 1.0f);
              G[(mt*16 + quad*4 + reg)*136 + wid*32 + nt*16 + l4] = (short)f2bf(gl);
            }
          }
        }
        // hoist m2 weight loads above the barrier (global, LDS-independent)
        s8v b2f[2][4];
        #pragma unroll
        for (int nt = 0; nt < 2; ++nt) {
          int c = wid*32 + nt*16 + l4;
          #pragma unroll
          for (int k0 = 0; k0 < 4; ++k0)
            b2f[nt][k0] = *(const s8v*)(m2Tl + c*512 + cc*128 + k0*32 + quad*8);
        }
        __syncthreads();
        s8v at4[4][4];
        #pragma unroll
        for (int mt = 0; mt < 4; ++mt)
          #pragma unroll
          for (int k0 = 0; k0 < 4; ++k0)
            at4[mt][k0] = *(const s8v*)(G + (mt*16 + l4)*136 + k0*32 + quad*8);
        #pragma unroll
        for (int nt = 0; nt < 2; ++nt) {
          #pragma unroll
          for (int mt = 0; mt < 4; ++mt) {
            f4v a2 = {xr[mt][nt][0], xr[mt][nt][1], xr[mt][nt][2], xr[mt][nt][3]};
            #pragma unroll
            for (int k0 = 0; k0 < 4; ++k0)
              a2 = MFMA16(at4[mt][k0], b2f[nt][k0], a2);
            #pragma unroll
            for (int reg = 0; reg < 4; ++reg)
              xr[mt][nt][reg] = a2[reg];
          }
        }
      }
      #pragma unroll
      for (int nt = 0; nt < 2; ++nt) {
        float b = m2bl[wid*32 + nt*16 + l4];
        #pragma unroll
        for (int mt = 0; mt < 4; ++mt)
          #pragma unroll
          for (int reg = 0; reg < 4; ++reg)
            xr[mt][nt][reg] += b;
      }
    }
  }

  #pragma unroll
  for (int mt = 0; mt < 4; ++mt)
    #pragma unroll
    for (int nt = 0; nt < 2; ++nt)
      #pragma unroll
      for (int reg = 0; reg < 4; ++reg)
        xg[(mt*16 + quad*4 + reg)*128 + wid*32 + nt*16 + l4] = (short)f2bf(xr[mt][nt][reg]);
}

// ---------------- gather + GNN linear (bf16 in/out) ----------------
__global__ __launch_bounds__(256) void k_gnn(
    const short* __restrict__ feat, const int* __restrict__ nef,
    const int* __restrict__ corr, const int* __restrict__ centers,
    const int* __restrict__ nef2, const short* __restrict__ gnnT,
    short* __restrict__ out) {
  __shared__ __align__(16) short Ab[64 * 264];
  int n = blockIdx.x, t = threadIdx.x;
  int wid = t >> 6, lane = t & 63, l4 = lane & 15, quad = lane >> 4;
  int j = t >> 2, qq = t & 3;
  int e  = iclamp(nef[n*64 + j], 0, N_EDGE - 1);
  int ce = iclamp(corr[e], 0, N_EDGE - 1);
  size_t r1 = ((size_t)iclamp(centers[e],  0, N_NODES-1) * 64 + iclamp(nef2[e],  0, 63)) * 128;
  size_t r2 = ((size_t)iclamp(centers[ce], 0, N_NODES-1) * 64 + iclamp(nef2[ce], 0, 63)) * 128;
  {
    const s8v* p1 = (const s8v*)(feat + r1 + qq*32);
    const s8v* p2 = (const s8v*)(feat + r2 + qq*32);
    #pragma unroll
    for (int ii = 0; ii < 4; ++ii) {
      *(s8v*)(Ab + j*264 + qq*32 + ii*8)       = p1[ii];
      *(s8v*)(Ab + j*264 + 128 + qq*32 + ii*8) = p2[ii];
    }
  }
  __syncthreads();
  f4v acc[4][2];
  #pragma unroll
  for (int mt = 0; mt < 4; ++mt)
    #pragma unroll
    for (int nt = 0; nt < 2; ++nt) { f4v zz = {0.f,0.f,0.f,0.f}; acc[mt][nt] = zz; }
  #pragma unroll
  for (int k0 = 0; k0 < 8; ++k0) {
    s8v a[4];
    #pragma unroll
    for (int mt = 0; mt < 4; ++mt)
      a[mt] = *(const s8v*)(Ab + (mt*16 + l4)*264 + k0*32 + quad*8);
    #pragma unroll
    for (int nt = 0; nt < 2; ++nt) {
      s8v b = *(const s8v*)(gnnT + (wid*32 + nt*16 + l4)*256 + k0*32 + quad*8);
      #pragma unroll
      for (int mt = 0; mt < 4; ++mt)
        acc[mt][nt] = MFMA16(a[mt], b, acc[mt][nt]);
    }
  }
  #pragma unroll
  for (int mt = 0; mt < 4; ++mt)
    #pragma unroll
    for (int nt = 0; nt < 2; ++nt)
      #pragma unroll
      for (int reg = 0; reg < 4; ++reg)
        out[((size_t)n*64 + mt*16 + quad*4 + reg)*128 + wid*32 + nt*16 + l4] =
            (short)f2bf(acc[mt][nt][reg]);
}

// ---------------- final masked sum + head ----------------
__global__ __launch_bounds__(256) void k_final(
    const short* __restrict__ feat, const short* __restrict__ buf2,
    const float* __restrict__ rm, const float* __restrict__ lastw,
    const float* __restrict__ compw, const int* __restrict__ species,
    float* __restrict__ out) {
  __shared__ float part[4];
  int n = blockIdx.x, t = threadIdx.x;
  int wid = t >> 6, lane = t & 63;
  int j = t >> 2, qq = t & 3;
  size_t base = ((size_t)n*64 + j)*128 + qq*32;
  float s = 0.f;
  #pragma unroll
  for (int i = 0; i < 32; ++i)
    s += (bf2f(feat[base + i]) + bf2f(buf2[base + i])) * lastw[qq*32 + i];
  s += __shfl_xor(s, 1);
  s += __shfl_xor(s, 2);
  float v = (qq == 0) ? s * rm[n*64 + j] : 0.f;
  v += __shfl_xor(v, 4);  v += __shfl_xor(v, 8);
  v += __shfl_xor(v, 16); v += __shfl_xor(v, 32);
  if (lane == 0) part[wid] = v;
  __syncthreads();
  if (t == 0) out[n] = part[0] + part[1] + part[2] + part[3]
                       + compw[iclamp(species[n], 0, 3)];
}

// ---------------- host ----------------

extern "C" void kernel_launch(void* const* d_in, const int* in_sizes, int n_in,
                              void* d_out, int out_size, void* d_ws, size_t ws_size,
                              hipStream_t stream) {
  const float* ev      = (const float*)d_in[0];
  const float* cart    = (const float*)d_in[1];
  const float* cemb    = (const float*)d_in[2];
  const float* nemb    = (const float*)d_in[3];
  const float* comp    = (const float*)d_in[4];
  const float* gnnw    = (const float*)d_in[5];
  const float* lastw   = (const float*)d_in[6];
  const float* compw   = (const float*)d_in[7];
  const int*   species = (const int*)d_in[8];
  const int*   centers = (const int*)d_in[9];
  const int*   neighbors = (const int*)d_in[10];
  const int*   nef     = (const int*)d_in[11];
  /* d_in[12] = nef_mask: unused (masked slots are provably inert) */
  const int*   nef2    = (const int*)d_in[13];
  const int*   corr    = (const int*)d_in[14];

  // workspace layout (bytes)
  const size_t OFF_RM   = 0;           // 1,048,576
  const size_t OFF_FEAT = 1048576;     // 67,108,864 (bf16)
  const size_t OFF_BUF2 = 68157440;    // 67,108,864 (bf16)
  const size_t OFF_TABS = 135266304;   // 5,632
  const size_t OFF_WBF  = 135271936;   // 1,638,400
  const size_t NEED     = 136910336;
  if (ws_size < NEED) return;  // insufficient scratch: fail cleanly, not a fault

  char* ws = (char*)d_ws;
  float* rm   = (float*)(ws + OFF_RM);
  short* feat = (short*)(ws + OFF_FEAT);
  short* buf2 = (short*)(ws + OFF_BUF2);
  float* tabs = (float*)(ws + OFF_TABS);
  short* wbf  = (short*)(ws + OFF_WBF);

  short* t0q  = wbf + 0;       // 2x(384x128)
  short* t0o  = wbf + 98304;   // 2x(128x128)
  short* t0m1 = wbf + 131072;  // 2x(512x128)
  short* t0m2 = wbf + 262144;  // 2x(128x512)
  short* t1q  = wbf + 393216;
  short* t1o  = wbf + 491520;
  short* t1m1 = wbf + 524288;
  short* t1m2 = wbf + 655360;
  short* gnnT = wbf + 786432;  // 128x256

  hipMemsetAsync(rm, 0, 4096*64*sizeof(float), stream);

  k_tr<<<384, 256, 0, stream>>>((const float*)d_in[17], t0q,  2, 128, 384);
  k_tr<<<128, 256, 0, stream>>>((const float*)d_in[19], t0o,  2, 128, 128);
  k_tr<<<512, 256, 0, stream>>>((const float*)d_in[23], t0m1, 2, 128, 512);
  k_tr<<<512, 256, 0, stream>>>((const float*)d_in[25], t0m2, 2, 512, 128);
  k_tr<<<384, 256, 0, stream>>>((const float*)d_in[29], t1q,  2, 128, 384);
  k_tr<<<128, 256, 0, stream>>>((const float*)d_in[31], t1o,  2, 128, 128);
  k_tr<<<512, 256, 0, stream>>>((const float*)d_in[35], t1m1, 2, 128, 512);
  k_tr<<<512, 256, 0, stream>>>((const float*)d_in[37], t1m2, 2, 512, 128);
  k_tr<<<128, 256, 0, stream>>>(gnnw, gnnT, 1, 256, 128);
  k_tabs<<<6, 256, 0, stream>>>(cart, cemb, nemb, comp, tabs);
  k_rm<<<512, 256, 0, stream>>>(ev, centers, nef2, rm);
  k_enc<<<4096, 256, 0, stream>>>(ev, nef, centers, neighbors, species, tabs, feat);

  k_tf<<<4096, 256, 0, stream>>>(feat, rm,
      (const float*)d_in[15], (const float*)d_in[16], t0q, (const float*)d_in[18],
      t0o, (const float*)d_in[20], (const float*)d_in[21], (const float*)d_in[22],
      t0m1, (const float*)d_in[24], t0m2, (const float*)d_in[26]);

  k_gnn<<<4096, 256, 0, stream>>>(feat, nef, corr, centers, nef2, gnnT, buf2);

  k_tf<<<4096, 256, 0, stream>>>(buf2, rm,
      (const float*)d_in[27], (const float*)d_in[28], t1q, (const float*)d_in[30],
      t1o, (const float*)d_in[32], (const float*)d_in[33], (const float*)d_in[34],
      t1m1, (const float*)d_in[36], t1m2, (const float*)d_in[38]);

  k_final<<<4096, 256, 0, stream>>>(feat, buf2, rm, lastw, compw, species, (float*)d_out);
}

// Round 7
// 1656.988 us; speedup vs baseline: 1.2811x; 1.2811x over previous
//
#include <hip/hip_runtime.h>

typedef short s8v __attribute__((ext_vector_type(8)));
typedef float f4v __attribute__((ext_vector_type(4)));

#define MFMA16(a,b,c) __builtin_amdgcn_mfma_f32_16x16x32_bf16((a),(b),(c),0,0,0)

#define N_NODES 4096
#define N_EDGE  131072
#define ATT_SCALE 0.17677669529663687f   // 1/sqrt(32)
#define NGC2     -1.5957691216057308f    // -2*sqrt(2/pi)

// fast path (hot kernel): round-half-up, 2 VALU
__device__ __forceinline__ unsigned short f2bf(float f) {
  union { float f; unsigned u; } v; v.f = f;
  return (unsigned short)((v.u + 0x8000u) >> 16);
}
// precise path (one-time prep): RNE
__device__ __forceinline__ unsigned short f2bf_rne(float f) {
  union { float f; unsigned u; } v; v.f = f;
  unsigned r = v.u + 0x7fffu + ((v.u >> 16) & 1u);
  return (unsigned short)(r >> 16);
}
__device__ __forceinline__ float bf2f(short s) {
  union { unsigned u; float f; } v;
  v.u = ((unsigned)(unsigned short)s) << 16;
  return v.f;
}
__device__ __forceinline__ int iclamp(int v, int lo, int hi) {
  return v < lo ? lo : (v > hi ? hi : v);
}

// ---------------- prep kernels ----------------

__global__ void k_tr(const float* __restrict__ src, short* __restrict__ dst,
                     int L, int K, int N) {
  int idx = blockIdx.x * 256 + threadIdx.x;
  int tot = L * K * N;
  if (idx >= tot) return;
  int l = idx / (K * N);
  int r = idx - l * (K * N);
  int k = r / N;
  int n = r - k * N;
  dst[l * K * N + n * K + k] = (short)f2bf_rne(src[idx]);
}

__global__ void k_tabs(const float* __restrict__ cart, const float* __restrict__ cemb,
                       const float* __restrict__ nemb, const float* __restrict__ comp,
                       float* __restrict__ tabs) {
  int idx = blockIdx.x * 256 + threadIdx.x;
  if (idx >= 1408) return;
  float s = 0.f;
  if (idx < 384) {
    int i = idx >> 7, d = idx & 127;
    for (int j = 0; j < 128; ++j) s += cart[i * 128 + j] * comp[j * 128 + d];
  } else if (idx < 896) {
    int i2 = idx - 384; int sp = i2 >> 7, d = i2 & 127;
    for (int j = 0; j < 128; ++j) s += cemb[sp * 128 + j] * comp[(128 + j) * 128 + d];
  } else {
    int i2 = idx - 896; int sp = i2 >> 7, d = i2 & 127;
    for (int j = 0; j < 128; ++j) s += nemb[sp * 128 + j] * comp[(256 + j) * 128 + d];
  }
  tabs[idx] = s;
}

__global__ void k_rm(const float* __restrict__ ev, const int* __restrict__ centers,
                     const int* __restrict__ nef2, float* __restrict__ rm) {
  int e = blockIdx.x * 256 + threadIdx.x;
  if (e >= N_EDGE) return;
  float x = ev[e*3], y = ev[e*3+1], z = ev[e*3+2];
  float r = sqrtf(x*x + y*y + z*z);
  float rad;
  if (r < 3.0f)      rad = 1.0f;
  else if (r < 5.0f) rad = 0.5f * (cosf(3.14159265358979f * (r - 3.0f) * 0.5f) + 1.0f);
  else               rad = 0.0f;
  int c  = iclamp(centers[e], 0, N_NODES - 1);
  int rk = iclamp(nef2[e], 0, 63);
  rm[c * 64 + rk] = rad;
}

__global__ __launch_bounds__(256) void k_enc(
    const float* __restrict__ ev, const int* __restrict__ nef,
    const int* __restrict__ centers, const int* __restrict__ neighbors,
    const int* __restrict__ species, const float* __restrict__ tabs,
    short* __restrict__ feat) {
  int n = blockIdx.x, t = threadIdx.x, j = t >> 2, qq = t & 3;
  int e = iclamp(nef[n * 64 + j], 0, N_EDGE - 1);
  float e0 = ev[e*3], e1 = ev[e*3+1], e2 = ev[e*3+2];
  int nc = iclamp(centers[e],   0, N_NODES - 1);
  int nn = iclamp(neighbors[e], 0, N_NODES - 1);
  int sc = iclamp(species[nc], 0, 3), sn = iclamp(species[nn], 0, 3);
  const float* m0 = tabs + qq*32;
  const float* m1 = tabs + 128 + qq*32;
  const float* m2 = tabs + 256 + qq*32;
  const float* tc = tabs + 384 + sc*128 + qq*32;
  const float* tn = tabs + 896 + sn*128 + qq*32;
  short* o = feat + ((size_t)(n*64 + j))*128 + qq*32;
  #pragma unroll
  for (int i = 0; i < 32; i += 2) {
    float a = e0*m0[i]   + e1*m1[i]   + e2*m2[i]   + tc[i]   + tn[i];
    float b = e0*m0[i+1] + e1*m1[i+1] + e2*m2[i+1] + tc[i+1] + tn[i+1];
    *(unsigned*)(o + i) = (unsigned)f2bf_rne(a) | ((unsigned)f2bf_rne(b) << 16);
  }
}

// ---------------- fused transformer (2 layers), static 52KB LDS ----------------
// block = one node; 4 waves partition columns. Residual x in f32 regs,
// MFMA C-layout: row = mt*16+quad*4+reg, col = wid*32+nt*16+l4.
// LDS: hb (17408) | kb (17408) | vtb (18432, red 2048 aliased at its base).
// Register model (rounds 2-6): gfx950 unified RF, compiler reserves AGPR ~= arch
// VGPR (even split). launch_bounds(256,2) -> 256 combined -> arch 128. To fit
// arch 128 WITHOUT spills: all GEMM phases split into 32-row halves AND the
// multi-trip loops (j=6, cc=4, hh where xr untouched) get #pragma unroll 1 so
// the scheduler can't hoist 4-6 iterations of weight loads (that hoisting is
// what spilled R5 despite halving). xr-indexing loops stay fully unrolled
// (dynamic index would send xr to scratch).

__device__ __forceinline__ void ln_sub(float (&xr)[4][2][4],
                                       const float* __restrict__ gw, const float* __restrict__ gb,
                                       float* red, short* hb, int wid, int quad, int l4) {
  #pragma unroll
  for (int mt = 0; mt < 4; ++mt)
    #pragma unroll
    for (int reg = 0; reg < 4; ++reg) {
      float a = xr[mt][0][reg] + xr[mt][1][reg];
      float s = xr[mt][0][reg]*xr[mt][0][reg] + xr[mt][1][reg]*xr[mt][1][reg];
      #pragma unroll
      for (int m = 1; m < 16; m <<= 1) { a += __shfl_xor(a, m); s += __shfl_xor(s, m); }
      if (l4 == 0) {
        int r = mt*16 + quad*4 + reg;
        red[(wid*64 + r)*2]     = a;
        red[(wid*64 + r)*2 + 1] = s;
      }
    }
  __syncthreads();
  int tid = threadIdx.x;
  if (tid < 64) {
    float a = 0.f, s = 0.f;
    #pragma unroll
    for (int w = 0; w < 4; ++w) { a += red[(w*64 + tid)*2]; s += red[(w*64 + tid)*2 + 1]; }
    float mean = a * (1.f/128.f);
    float var  = s * (1.f/128.f) - mean*mean;
    red[tid*2]     = mean;
    red[tid*2 + 1] = rsqrtf(var + 1e-5f);
  }
  __syncthreads();
  float gv[2], bv[2];
  #pragma unroll
  for (int nt = 0; nt < 2; ++nt) { int c = wid*32 + nt*16 + l4; gv[nt] = gw[c]; bv[nt] = gb[c]; }
  #pragma unroll
  for (int mt = 0; mt < 4; ++mt)
    #pragma unroll
    for (int reg = 0; reg < 4; ++reg) {
      int r = mt*16 + quad*4 + reg;
      float mean = red[r*2], inv = red[r*2 + 1];
      #pragma unroll
      for (int nt = 0; nt < 2; ++nt) {
        float h = (xr[mt][nt][reg] - mean) * inv * gv[nt] + bv[nt];
        hb[r*136 + wid*32 + nt*16 + l4] = (short)f2bf(h);
      }
    }
  __syncthreads();
}

__global__ __launch_bounds__(256, 2) void k_tf(
    short* __restrict__ x, const float* __restrict__ rm,
    const float* __restrict__ lnw1, const float* __restrict__ lnb1,
    const short* __restrict__ qkvT, const float* __restrict__ qkvb,
    const short* __restrict__ outT, const float* __restrict__ outb,
    const float* __restrict__ lnw2, const float* __restrict__ lnb2,
    const short* __restrict__ m1T, const float* __restrict__ m1b,
    const short* __restrict__ m2T, const float* __restrict__ m2b) {
  __shared__ __align__(16) char smem[53248];
  short* hb  = (short*)smem;              // 17408 B: LN-out / q / attn-out
  short* kb  = (short*)(smem + 17408);    // 17408 B: k ; P-scratch (own cols); MLP G0
  short* vtb = (short*)(smem + 34816);    // 18432 B: V^T [feat128][key stride 72]; MLP G1
  float* red = (float*)(smem + 34816);    // 2048 B aliased at vtb base (LN phases only)

  const int tid = threadIdx.x;
  const int wid = tid >> 6;
  const int lane = tid & 63;
  const int l4 = lane & 15;
  const int quad = lane >> 4;
  const int n = blockIdx.x;

  float rv[4];
  #pragma unroll
  for (int n2 = 0; n2 < 4; ++n2) rv[n2] = rm[n*64 + n2*16 + l4];

  short* xg = x + (size_t)n * 64 * 128;
  float xr[4][2][4];
  #pragma unroll
  for (int mt = 0; mt < 4; ++mt)
    #pragma unroll
    for (int nt = 0; nt < 2; ++nt)
      #pragma unroll
      for (int reg = 0; reg < 4; ++reg)
        xr[mt][nt][reg] = bf2f(xg[(mt*16 + quad*4 + reg)*128 + wid*32 + nt*16 + l4]);

  for (int l = 0; l < 2; ++l) {
    const float* g1    = lnw1 + l*128;   const float* bb1   = lnb1 + l*128;
    const short* qkvTl = qkvT + l*49152; const float* qkvbl = qkvb + l*384;
    const short* outTl = outT + l*16384; const float* outbl = outb + l*128;
    const float* g2    = lnw2 + l*128;   const float* bb2   = lnb2 + l*128;
    const short* m1Tl  = m1T + l*65536;  const float* m1bl  = m1b + l*512;
    const short* m2Tl  = m2T + l*65536;  const float* m2bl  = m2b + l*128;

    // guard red(=vtb) writes vs previous layer's MLP G1 reads
    __syncthreads();

    ln_sub(xr, g1, bb1, red, hb, wid, quad, l4);   // -> hb, trailing barrier

    // ---- QKV in two 32-row halves (no xr use: unroll-disabled loops) ----
    #pragma unroll 1
    for (int hh = 0; hh < 2; ++hh) {
      s8v af[2][4];
      #pragma unroll
      for (int m2 = 0; m2 < 2; ++m2)
        #pragma unroll
        for (int k0 = 0; k0 < 4; ++k0)
          af[m2][k0] = *(const s8v*)(hb + ((hh*2 + m2)*16 + l4)*136 + k0*32 + quad*8);
      __syncthreads();   // all waves hold this half's h rows; safe to overwrite

      #pragma unroll 1
      for (int j = 0; j < 6; ++j) {
        int col = wid*96 + j*16 + l4;
        s8v bf[4];
        #pragma unroll
        for (int k0 = 0; k0 < 4; ++k0)
          bf[k0] = *(const s8v*)(qkvTl + col*128 + k0*32 + quad*8);
        float bias = qkvbl[col];
        f4v acc[2];
        #pragma unroll
        for (int m2 = 0; m2 < 2; ++m2) { f4v bb = {bias,bias,bias,bias}; acc[m2] = bb; }
        #pragma unroll
        for (int k0 = 0; k0 < 4; ++k0)
          #pragma unroll
          for (int m2 = 0; m2 < 2; ++m2)
            acc[m2] = MFMA16(af[m2][k0], bf[k0], acc[m2]);
        if (col < 128) {
          #pragma unroll
          for (int m2 = 0; m2 < 2; ++m2)
            #pragma unroll
            for (int reg = 0; reg < 4; ++reg)
              hb[((hh*2+m2)*16 + quad*4 + reg)*136 + col] = (short)f2bf(acc[m2][reg] * ATT_SCALE);
        } else if (col < 256) {
          int c = col - 128;
          #pragma unroll
          for (int m2 = 0; m2 < 2; ++m2)
            #pragma unroll
            for (int reg = 0; reg < 4; ++reg)
              kb[((hh*2+m2)*16 + quad*4 + reg)*136 + c] = (short)f2bf(acc[m2][reg]);
        } else {
          int c = col - 256;
          #pragma unroll
          for (int m2 = 0; m2 < 2; ++m2)
            #pragma unroll
            for (int reg = 0; reg < 4; ++reg)
              vtb[c*72 + (hh*2+m2)*16 + quad*4 + reg] = (short)f2bf(acc[m2][reg]);
        }
      }
    }
    __syncthreads();

    // ---- attention: wave = head; zero internal barriers; two query-halves ----
    {
      const int h = wid;
      s8v bk[4];
      #pragma unroll
      for (int n2 = 0; n2 < 4; ++n2)
        bk[n2] = *(const s8v*)(kb + (n2*16 + l4)*136 + h*32 + quad*8);

      #pragma unroll 1
      for (int hh = 0; hh < 2; ++hh) {
        s8v aq[2];
        #pragma unroll
        for (int m2 = 0; m2 < 2; ++m2)
          aq[m2] = *(const s8v*)(hb + ((hh*2+m2)*16 + l4)*136 + h*32 + quad*8);
        f4v S[2][4];
        #pragma unroll
        for (int m2 = 0; m2 < 2; ++m2)
          #pragma unroll
          for (int n2 = 0; n2 < 4; ++n2) {
            f4v zz = {0.f,0.f,0.f,0.f};
            S[m2][n2] = MFMA16(aq[m2], bk[n2], zz);
          }

        #pragma unroll
        for (int m2 = 0; m2 < 2; ++m2)
          #pragma unroll
          for (int reg = 0; reg < 4; ++reg) {
            float mx = fmaxf(fmaxf(S[m2][0][reg], S[m2][1][reg]),
                             fmaxf(S[m2][2][reg], S[m2][3][reg]));
            mx = fmaxf(mx, __shfl_xor(mx, 1));
            mx = fmaxf(mx, __shfl_xor(mx, 2));
            mx = fmaxf(mx, __shfl_xor(mx, 4));
            mx = fmaxf(mx, __shfl_xor(mx, 8));
            float E = 0.f, W = 0.f;
            #pragma unroll
            for (int n2 = 0; n2 < 4; ++n2) {
              float e = __expf(S[m2][n2][reg] - mx);
              E += e; W += e * rv[n2];
              S[m2][n2][reg] = e * rv[n2];
            }
            E += __shfl_xor(E, 1); E += __shfl_xor(E, 2);
            E += __shfl_xor(E, 4); E += __shfl_xor(E, 8);
            W += __shfl_xor(W, 1); W += __shfl_xor(W, 2);
            W += __shfl_xor(W, 4); W += __shfl_xor(W, 8);
            float inv = __builtin_amdgcn_rcpf(W + 1e-9f * E);
            #pragma unroll
            for (int n2 = 0; n2 < 4; ++n2) S[m2][n2][reg] *= inv;
          }

        // PV in 32-key chunks; P transposed through own kb columns
        f4v o[2][2];
        #pragma unroll
        for (int m2 = 0; m2 < 2; ++m2)
          #pragma unroll
          for (int nt = 0; nt < 2; ++nt) { f4v zz = {0.f,0.f,0.f,0.f}; o[m2][nt] = zz; }
        #pragma unroll
        for (int c = 0; c < 2; ++c) {
          #pragma unroll
          for (int m2 = 0; m2 < 2; ++m2)
            #pragma unroll
            for (int n2 = 0; n2 < 2; ++n2)
              #pragma unroll
              for (int reg = 0; reg < 4; ++reg)
                kb[((hh*2+m2)*16 + quad*4 + reg)*136 + h*32 + n2*16 + l4] =
                    (short)f2bf(S[m2][2*c + n2][reg]);
          s8v ap[2];
          #pragma unroll
          for (int m2 = 0; m2 < 2; ++m2)
            ap[m2] = *(const s8v*)(kb + ((hh*2+m2)*16 + l4)*136 + h*32 + quad*8);
          #pragma unroll
          for (int nt = 0; nt < 2; ++nt) {
            s8v bv = *(const s8v*)(vtb + (h*32 + nt*16 + l4)*72 + c*32 + quad*8);
            #pragma unroll
            for (int m2 = 0; m2 < 2; ++m2)
              o[m2][nt] = MFMA16(ap[m2], bv, o[m2][nt]);
          }
        }
        #pragma unroll
        for (int m2 = 0; m2 < 2; ++m2)
          #pragma unroll
          for (int nt = 0; nt < 2; ++nt)
            #pragma unroll
            for (int reg = 0; reg < 4; ++reg)
              hb[((hh*2+m2)*16 + quad*4 + reg)*136 + h*32 + nt*16 + l4] =
                  (short)f2bf(o[m2][nt][reg]);
      }
    }
    __syncthreads();

    // ---- output proj + residual (xr-indexed: keep unrolled) ----
    #pragma unroll
    for (int hh = 0; hh < 2; ++hh) {
      s8v ao[2][4];
      #pragma unroll
      for (int m2 = 0; m2 < 2; ++m2)
        #pragma unroll
        for (int k0 = 0; k0 < 4; ++k0)
          ao[m2][k0] = *(const s8v*)(hb + ((hh*2+m2)*16 + l4)*136 + k0*32 + quad*8);
      #pragma unroll
      for (int nt = 0; nt < 2; ++nt) {
        int c = wid*32 + nt*16 + l4;
        s8v bo[4];
        #pragma unroll
        for (int k0 = 0; k0 < 4; ++k0)
          bo[k0] = *(const s8v*)(outTl + c*128 + k0*32 + quad*8);
        float bias = outbl[c];
        #pragma unroll
        for (int m2 = 0; m2 < 2; ++m2) {
          int mt = hh*2 + m2;
          f4v a2 = {xr[mt][nt][0] + bias, xr[mt][nt][1] + bias,
                    xr[mt][nt][2] + bias, xr[mt][nt][3] + bias};
          #pragma unroll
          for (int k0 = 0; k0 < 4; ++k0)
            a2 = MFMA16(ao[m2][k0], bo[k0], a2);
          #pragma unroll
          for (int reg = 0; reg < 4; ++reg)
            xr[mt][nt][reg] = a2[reg];
        }
      }
    }

    ln_sub(xr, g2, bb2, red, hb, wid, quad, l4);   // LN2 -> hb

    // ---- MLP: gelu double-buffered kb/vtb; 1 barrier per chunk; halves ----
    #pragma unroll 1
    for (int cc = 0; cc < 4; ++cc) {
      short* G = (cc & 1) ? vtb : kb;
      #pragma unroll 1
      for (int hh = 0; hh < 2; ++hh) {
        s8v afm[2][4];
        #pragma unroll
        for (int m2 = 0; m2 < 2; ++m2)
          #pragma unroll
          for (int k0 = 0; k0 < 4; ++k0)
            afm[m2][k0] = *(const s8v*)(hb + ((hh*2+m2)*16 + l4)*136 + k0*32 + quad*8);
        #pragma unroll
        for (int nt = 0; nt < 2; ++nt) {
          int jc = cc*128 + wid*32 + nt*16 + l4;
          s8v bm[4];
          #pragma unroll
          for (int k0 = 0; k0 < 4; ++k0)
            bm[k0] = *(const s8v*)(m1Tl + jc*128 + k0*32 + quad*8);
          float bias = m1bl[jc];
          #pragma unroll
          for (int m2 = 0; m2 < 2; ++m2) {
            f4v a2 = {bias, bias, bias, bias};
            #pragma unroll
            for (int k0 = 0; k0 < 4; ++k0)
              a2 = MFMA16(afm[m2][k0], bm[k0], a2);
            #pragma unroll
            for (int reg = 0; reg < 4; ++reg) {
              // gelu(v) = v * sigmoid(2*sqrt(2/pi)*(v + 0.044715 v^3))
              float v = a2[reg];
              float t = v * v;
              float u = fmaf(0.044715f, t, 1.0f);
              float w = v * u;
              float e = __expf(NGC2 * w);
              float gl = v * __builtin_amdgcn_rcpf(e + 1.0f);
              G[((hh*2+m2)*16 + quad*4 + reg)*136 + wid*32 + nt*16 + l4] = (short)f2bf(gl);
            }
          }
        }
      }
      __syncthreads();
      #pragma unroll
      for (int hh = 0; hh < 2; ++hh) {
        s8v at4[2][4];
        #pragma unroll
        for (int m2 = 0; m2 < 2; ++m2)
          #pragma unroll
          for (int k0 = 0; k0 < 4; ++k0)
            at4[m2][k0] = *(const s8v*)(G + ((hh*2+m2)*16 + l4)*136 + k0*32 + quad*8);
        #pragma unroll
        for (int nt = 0; nt < 2; ++nt) {
          int c = wid*32 + nt*16 + l4;
          s8v b2f[4];
          #pragma unroll
          for (int k0 = 0; k0 < 4; ++k0)
            b2f[k0] = *(const s8v*)(m2Tl + c*512 + cc*128 + k0*32 + quad*8);
          #pragma unroll
          for (int m2 = 0; m2 < 2; ++m2) {
            int mt = hh*2 + m2;
            f4v a2 = {xr[mt][nt][0], xr[mt][nt][1], xr[mt][nt][2], xr[mt][nt][3]};
            #pragma unroll
            for (int k0 = 0; k0 < 4; ++k0)
              a2 = MFMA16(at4[m2][k0], b2f[k0], a2);
            #pragma unroll
            for (int reg = 0; reg < 4; ++reg)
              xr[mt][nt][reg] = a2[reg];
          }
        }
      }
    }
    #pragma unroll
    for (int nt = 0; nt < 2; ++nt) {
      float b = m2bl[wid*32 + nt*16 + l4];
      #pragma unroll
      for (int mt = 0; mt < 4; ++mt)
        #pragma unroll
        for (int reg = 0; reg < 4; ++reg)
          xr[mt][nt][reg] += b;
    }
  }

  #pragma unroll
  for (int mt = 0; mt < 4; ++mt)
    #pragma unroll
    for (int nt = 0; nt < 2; ++nt)
      #pragma unroll
      for (int reg = 0; reg < 4; ++reg)
        xg[(mt*16 + quad*4 + reg)*128 + wid*32 + nt*16 + l4] = (short)f2bf(xr[mt][nt][reg]);
}

// ---------------- gather + GNN linear (bf16 in/out) ----------------
__global__ __launch_bounds__(256) void k_gnn(
    const short* __restrict__ feat, const int* __restrict__ nef,
    const int* __restrict__ corr, const int* __restrict__ centers,
    const int* __restrict__ nef2, const short* __restrict__ gnnT,
    short* __restrict__ out) {
  __shared__ __align__(16) short Ab[64 * 264];
  int n = blockIdx.x, t = threadIdx.x;
  int wid = t >> 6, lane = t & 63, l4 = lane & 15, quad = lane >> 4;
  int j = t >> 2, qq = t & 3;
  int e  = iclamp(nef[n*64 + j], 0, N_EDGE - 1);
  int ce = iclamp(corr[e], 0, N_EDGE - 1);
  size_t r1 = ((size_t)iclamp(centers[e],  0, N_NODES-1) * 64 + iclamp(nef2[e],  0, 63)) * 128;
  size_t r2 = ((size_t)iclamp(centers[ce], 0, N_NODES-1) * 64 + iclamp(nef2[ce], 0, 63)) * 128;
  {
    const s8v* p1 = (const s8v*)(feat + r1 + qq*32);
    const s8v* p2 = (const s8v*)(feat + r2 + qq*32);
    #pragma unroll
    for (int ii = 0; ii < 4; ++ii) {
      *(s8v*)(Ab + j*264 + qq*32 + ii*8)       = p1[ii];
      *(s8v*)(Ab + j*264 + 128 + qq*32 + ii*8) = p2[ii];
    }
  }
  __syncthreads();
  f4v acc[4][2];
  #pragma unroll
  for (int mt = 0; mt < 4; ++mt)
    #pragma unroll
    for (int nt = 0; nt < 2; ++nt) { f4v zz = {0.f,0.f,0.f,0.f}; acc[mt][nt] = zz; }
  #pragma unroll
  for (int k0 = 0; k0 < 8; ++k0) {
    s8v a[4];
    #pragma unroll
    for (int mt = 0; mt < 4; ++mt)
      a[mt] = *(const s8v*)(Ab + (mt*16 + l4)*264 + k0*32 + quad*8);
    #pragma unroll
    for (int nt = 0; nt < 2; ++nt) {
      s8v b = *(const s8v*)(gnnT + (wid*32 + nt*16 + l4)*256 + k0*32 + quad*8);
      #pragma unroll
      for (int mt = 0; mt < 4; ++mt)
        acc[mt][nt] = MFMA16(a[mt], b, acc[mt][nt]);
    }
  }
  #pragma unroll
  for (int mt = 0; mt < 4; ++mt)
    #pragma unroll
    for (int nt = 0; nt < 2; ++nt)
      #pragma unroll
      for (int reg = 0; reg < 4; ++reg)
        out[((size_t)n*64 + mt*16 + quad*4 + reg)*128 + wid*32 + nt*16 + l4] =
            (short)f2bf(acc[mt][nt][reg]);
}

// ---------------- final masked sum + head ----------------
__global__ __launch_bounds__(256) void k_final(
    const short* __restrict__ feat, const short* __restrict__ buf2,
    const float* __restrict__ rm, const float* __restrict__ lastw,
    const float* __restrict__ compw, const int* __restrict__ species,
    float* __restrict__ out) {
  __shared__ float part[4];
  int n = blockIdx.x, t = threadIdx.x;
  int wid = t >> 6, lane = t & 63;
  int j = t >> 2, qq = t & 3;
  size_t base = ((size_t)n*64 + j)*128 + qq*32;
  float s = 0.f;
  #pragma unroll
  for (int i = 0; i < 32; ++i)
    s += (bf2f(feat[base + i]) + bf2f(buf2[base + i])) * lastw[qq*32 + i];
  s += __shfl_xor(s, 1);
  s += __shfl_xor(s, 2);
  float v = (qq == 0) ? s * rm[n*64 + j] : 0.f;
  v += __shfl_xor(v, 4);  v += __shfl_xor(v, 8);
  v += __shfl_xor(v, 16); v += __shfl_xor(v, 32);
  if (lane == 0) part[wid] = v;
  __syncthreads();
  if (t == 0) out[n] = part[0] + part[1] + part[2] + part[3]
                       + compw[iclamp(species[n], 0, 3)];
}

// ---------------- host ----------------

extern "C" void kernel_launch(void* const* d_in, const int* in_sizes, int n_in,
                              void* d_out, int out_size, void* d_ws, size_t ws_size,
                              hipStream_t stream) {
  const float* ev      = (const float*)d_in[0];
  const float* cart    = (const float*)d_in[1];
  const float* cemb    = (const float*)d_in[2];
  const float* nemb    = (const float*)d_in[3];
  const float* comp    = (const float*)d_in[4];
  const float* gnnw    = (const float*)d_in[5];
  const float* lastw   = (const float*)d_in[6];
  const float* compw   = (const float*)d_in[7];
  const int*   species = (const int*)d_in[8];
  const int*   centers = (const int*)d_in[9];
  const int*   neighbors = (const int*)d_in[10];
  const int*   nef     = (const int*)d_in[11];
  /* d_in[12] = nef_mask: unused (masked slots are provably inert) */
  const int*   nef2    = (const int*)d_in[13];
  const int*   corr    = (const int*)d_in[14];

  // workspace layout (bytes)
  const size_t OFF_RM   = 0;           // 1,048,576
  const size_t OFF_FEAT = 1048576;     // 67,108,864 (bf16)
  const size_t OFF_BUF2 = 68157440;    // 67,108,864 (bf16)
  const size_t OFF_TABS = 135266304;   // 5,632
  const size_t OFF_WBF  = 135271936;   // 1,638,400
  const size_t NEED     = 136910336;
  if (ws_size < NEED) return;  // insufficient scratch: fail cleanly, not a fault

  char* ws = (char*)d_ws;
  float* rm   = (float*)(ws + OFF_RM);
  short* feat = (short*)(ws + OFF_FEAT);
  short* buf2 = (short*)(ws + OFF_BUF2);
  float* tabs = (float*)(ws + OFF_TABS);
  short* wbf  = (short*)(ws + OFF_WBF);

  short* t0q  = wbf + 0;       // 2x(384x128)
  short* t0o  = wbf + 98304;   // 2x(128x128)
  short* t0m1 = wbf + 131072;  // 2x(512x128)
  short* t0m2 = wbf + 262144;  // 2x(128x512)
  short* t1q  = wbf + 393216;
  short* t1o  = wbf + 491520;
  short* t1m1 = wbf + 524288;
  short* t1m2 = wbf + 655360;
  short* gnnT = wbf + 786432;  // 128x256

  hipMemsetAsync(rm, 0, 4096*64*sizeof(float), stream);

  k_tr<<<384, 256, 0, stream>>>((const float*)d_in[17], t0q,  2, 128, 384);
  k_tr<<<128, 256, 0, stream>>>((const float*)d_in[19], t0o,  2, 128, 128);
  k_tr<<<512, 256, 0, stream>>>((const float*)d_in[23], t0m1, 2, 128, 512);
  k_tr<<<512, 256, 0, stream>>>((const float*)d_in[25], t0m2, 2, 512, 128);
  k_tr<<<384, 256, 0, stream>>>((const float*)d_in[29], t1q,  2, 128, 384);
  k_tr<<<128, 256, 0, stream>>>((const float*)d_in[31], t1o,  2, 128, 128);
  k_tr<<<512, 256, 0, stream>>>((const float*)d_in[35], t1m1, 2, 128, 512);
  k_tr<<<512, 256, 0, stream>>>((const float*)d_in[37], t1m2, 2, 512, 128);
  k_tr<<<128, 256, 0, stream>>>(gnnw, gnnT, 1, 256, 128);
  k_tabs<<<6, 256, 0, stream>>>(cart, cemb, nemb, comp, tabs);
  k_rm<<<512, 256, 0, stream>>>(ev, centers, nef2, rm);
  k_enc<<<4096, 256, 0, stream>>>(ev, nef, centers, neighbors, species, tabs, feat);

  k_tf<<<4096, 256, 0, stream>>>(feat, rm,
      (const float*)d_in[15], (const float*)d_in[16], t0q, (const float*)d_in[18],
      t0o, (const float*)d_in[20], (const float*)d_in[21], (const float*)d_in[22],
      t0m1, (const float*)d_in[24], t0m2, (const float*)d_in[26]);

  k_gnn<<<4096, 256, 0, stream>>>(feat, nef, corr, centers, nef2, gnnT, buf2);

  k_tf<<<4096, 256, 0, stream>>>(buf2, rm,
      (const float*)d_in[27], (const float*)d_in[28], t1q, (const float*)d_in[30],
      t1o, (const float*)d_in[32], (const float*)d_in[33], (const float*)d_in[34],
      t1m1, (const float*)d_in[36], t1m2, (const float*)d_in[38]);

  k_final<<<4096, 256, 0, stream>>>(feat, buf2, rm, lastw, compw, species, (float*)d_out);
}

// Round 8
// 1621.952 us; speedup vs baseline: 1.3088x; 1.0216x over previous
//
#include <hip/hip_runtime.h>

typedef short s8v __attribute__((ext_vector_type(8)));
typedef float f4v __attribute__((ext_vector_type(4)));

#define MFMA16(a,b,c) __builtin_amdgcn_mfma_f32_16x16x32_bf16((a),(b),(c),0,0,0)

#define N_NODES 4096
#define N_EDGE  131072
#define ATT_SCALE 0.17677669529663687f   // 1/sqrt(32)
#define NGC2     -1.5957691216057308f    // -2*sqrt(2/pi)

// fast path (hot kernel): round-half-up, 2 VALU
__device__ __forceinline__ unsigned short f2bf(float f) {
  union { float f; unsigned u; } v; v.f = f;
  return (unsigned short)((v.u + 0x8000u) >> 16);
}
// precise path (one-time prep): RNE
__device__ __forceinline__ unsigned short f2bf_rne(float f) {
  union { float f; unsigned u; } v; v.f = f;
  unsigned r = v.u + 0x7fffu + ((v.u >> 16) & 1u);
  return (unsigned short)(r >> 16);
}
__device__ __forceinline__ float bf2f(short s) {
  union { unsigned u; float f; } v;
  v.u = ((unsigned)(unsigned short)s) << 16;
  return v.f;
}
__device__ __forceinline__ int iclamp(int v, int lo, int hi) {
  return v < lo ? lo : (v > hi ? hi : v);
}

// ---------------- prep kernels ----------------

__global__ void k_tr(const float* __restrict__ src, short* __restrict__ dst,
                     int L, int K, int N) {
  int idx = blockIdx.x * 256 + threadIdx.x;
  int tot = L * K * N;
  if (idx >= tot) return;
  int l = idx / (K * N);
  int r = idx - l * (K * N);
  int k = r / N;
  int n = r - k * N;
  dst[l * K * N + n * K + k] = (short)f2bf_rne(src[idx]);
}

__global__ void k_tabs(const float* __restrict__ cart, const float* __restrict__ cemb,
                       const float* __restrict__ nemb, const float* __restrict__ comp,
                       float* __restrict__ tabs) {
  int idx = blockIdx.x * 256 + threadIdx.x;
  if (idx >= 1408) return;
  float s = 0.f;
  if (idx < 384) {
    int i = idx >> 7, d = idx & 127;
    for (int j = 0; j < 128; ++j) s += cart[i * 128 + j] * comp[j * 128 + d];
  } else if (idx < 896) {
    int i2 = idx - 384; int sp = i2 >> 7, d = i2 & 127;
    for (int j = 0; j < 128; ++j) s += cemb[sp * 128 + j] * comp[(128 + j) * 128 + d];
  } else {
    int i2 = idx - 896; int sp = i2 >> 7, d = i2 & 127;
    for (int j = 0; j < 128; ++j) s += nemb[sp * 128 + j] * comp[(256 + j) * 128 + d];
  }
  tabs[idx] = s;
}

__global__ void k_rm(const float* __restrict__ ev, const int* __restrict__ centers,
                     const int* __restrict__ nef2, float* __restrict__ rm) {
  int e = blockIdx.x * 256 + threadIdx.x;
  if (e >= N_EDGE) return;
  float x = ev[e*3], y = ev[e*3+1], z = ev[e*3+2];
  float r = sqrtf(x*x + y*y + z*z);
  float rad;
  if (r < 3.0f)      rad = 1.0f;
  else if (r < 5.0f) rad = 0.5f * (cosf(3.14159265358979f * (r - 3.0f) * 0.5f) + 1.0f);
  else               rad = 0.0f;
  int c  = iclamp(centers[e], 0, N_NODES - 1);
  int rk = iclamp(nef2[e], 0, 63);
  rm[c * 64 + rk] = rad;
}

__global__ __launch_bounds__(256) void k_enc(
    const float* __restrict__ ev, const int* __restrict__ nef,
    const int* __restrict__ centers, const int* __restrict__ neighbors,
    const int* __restrict__ species, const float* __restrict__ tabs,
    short* __restrict__ feat) {
  int n = blockIdx.x, t = threadIdx.x, j = t >> 2, qq = t & 3;
  int e = iclamp(nef[n * 64 + j], 0, N_EDGE - 1);
  float e0 = ev[e*3], e1 = ev[e*3+1], e2 = ev[e*3+2];
  int nc = iclamp(centers[e],   0, N_NODES - 1);
  int nn = iclamp(neighbors[e], 0, N_NODES - 1);
  int sc = iclamp(species[nc], 0, 3), sn = iclamp(species[nn], 0, 3);
  const float* m0 = tabs + qq*32;
  const float* m1 = tabs + 128 + qq*32;
  const float* m2 = tabs + 256 + qq*32;
  const float* tc = tabs + 384 + sc*128 + qq*32;
  const float* tn = tabs + 896 + sn*128 + qq*32;
  short* o = feat + ((size_t)(n*64 + j))*128 + qq*32;
  #pragma unroll
  for (int i = 0; i < 32; i += 2) {
    float a = e0*m0[i]   + e1*m1[i]   + e2*m2[i]   + tc[i]   + tn[i];
    float b = e0*m0[i+1] + e1*m1[i+1] + e2*m2[i+1] + tc[i+1] + tn[i+1];
    *(unsigned*)(o + i) = (unsigned)f2bf_rne(a) | ((unsigned)f2bf_rne(b) << 16);
  }
}

// ---------------- fused transformer (2 layers), static 52KB LDS ----------------
// block = one node; 4 waves partition columns. Residual x in f32 regs,
// MFMA C-layout: row = mt*16+quad*4+reg, col = wid*32+nt*16+l4.
// LDS: hb (17408) | kb (17408) | vtb (18432, red 2048 aliased at its base).
// Register model (R2-R7): gfx950 unified RF, allocator reserves AGPR ~= arch
// VGPR. launch_bounds(256,2) -> arch budget 128. GEMM phases in 32-row halves,
// unroll 1 on weight-loop fences -> VGPR 120, zero spills (R7, 727us k_tf).
// R8: hide L2 weight-load latency: unroll 2 on QKV j-loop (scheduler hoists
// next iter's loads over MFMAs), MLP bm hoisted out of hh (was loaded 2x),
// b2f loaded BEFORE the barrier (latency overlaps barrier wait).

__device__ __forceinline__ void ln_sub(float (&xr)[4][2][4],
                                       const float* __restrict__ gw, const float* __restrict__ gb,
                                       float* red, short* hb, int wid, int quad, int l4) {
  #pragma unroll
  for (int mt = 0; mt < 4; ++mt)
    #pragma unroll
    for (int reg = 0; reg < 4; ++reg) {
      float a = xr[mt][0][reg] + xr[mt][1][reg];
      float s = xr[mt][0][reg]*xr[mt][0][reg] + xr[mt][1][reg]*xr[mt][1][reg];
      #pragma unroll
      for (int m = 1; m < 16; m <<= 1) { a += __shfl_xor(a, m); s += __shfl_xor(s, m); }
      if (l4 == 0) {
        int r = mt*16 + quad*4 + reg;
        red[(wid*64 + r)*2]     = a;
        red[(wid*64 + r)*2 + 1] = s;
      }
    }
  __syncthreads();
  int tid = threadIdx.x;
  if (tid < 64) {
    float a = 0.f, s = 0.f;
    #pragma unroll
    for (int w = 0; w < 4; ++w) { a += red[(w*64 + tid)*2]; s += red[(w*64 + tid)*2 + 1]; }
    float mean = a * (1.f/128.f);
    float var  = s * (1.f/128.f) - mean*mean;
    red[tid*2]     = mean;
    red[tid*2 + 1] = rsqrtf(var + 1e-5f);
  }
  __syncthreads();
  float gv[2], bv[2];
  #pragma unroll
  for (int nt = 0; nt < 2; ++nt) { int c = wid*32 + nt*16 + l4; gv[nt] = gw[c]; bv[nt] = gb[c]; }
  #pragma unroll
  for (int mt = 0; mt < 4; ++mt)
    #pragma unroll
    for (int reg = 0; reg < 4; ++reg) {
      int r = mt*16 + quad*4 + reg;
      float mean = red[r*2], inv = red[r*2 + 1];
      #pragma unroll
      for (int nt = 0; nt < 2; ++nt) {
        float h = (xr[mt][nt][reg] - mean) * inv * gv[nt] + bv[nt];
        hb[r*136 + wid*32 + nt*16 + l4] = (short)f2bf(h);
      }
    }
  __syncthreads();
}

__global__ __launch_bounds__(256, 2) void k_tf(
    short* __restrict__ x, const float* __restrict__ rm,
    const float* __restrict__ lnw1, const float* __restrict__ lnb1,
    const short* __restrict__ qkvT, const float* __restrict__ qkvb,
    const short* __restrict__ outT, const float* __restrict__ outb,
    const float* __restrict__ lnw2, const float* __restrict__ lnb2,
    const short* __restrict__ m1T, const float* __restrict__ m1b,
    const short* __restrict__ m2T, const float* __restrict__ m2b) {
  __shared__ __align__(16) char smem[53248];
  short* hb  = (short*)smem;              // 17408 B: LN-out / q / attn-out
  short* kb  = (short*)(smem + 17408);    // 17408 B: k ; P-scratch (own cols); MLP G0
  short* vtb = (short*)(smem + 34816);    // 18432 B: V^T [feat128][key stride 72]; MLP G1
  float* red = (float*)(smem + 34816);    // 2048 B aliased at vtb base (LN phases only)

  const int tid = threadIdx.x;
  const int wid = tid >> 6;
  const int lane = tid & 63;
  const int l4 = lane & 15;
  const int quad = lane >> 4;
  const int n = blockIdx.x;

  float rv[4];
  #pragma unroll
  for (int n2 = 0; n2 < 4; ++n2) rv[n2] = rm[n*64 + n2*16 + l4];

  short* xg = x + (size_t)n * 64 * 128;
  float xr[4][2][4];
  #pragma unroll
  for (int mt = 0; mt < 4; ++mt)
    #pragma unroll
    for (int nt = 0; nt < 2; ++nt)
      #pragma unroll
      for (int reg = 0; reg < 4; ++reg)
        xr[mt][nt][reg] = bf2f(xg[(mt*16 + quad*4 + reg)*128 + wid*32 + nt*16 + l4]);

  for (int l = 0; l < 2; ++l) {
    const float* g1    = lnw1 + l*128;   const float* bb1   = lnb1 + l*128;
    const short* qkvTl = qkvT + l*49152; const float* qkvbl = qkvb + l*384;
    const short* outTl = outT + l*16384; const float* outbl = outb + l*128;
    const float* g2    = lnw2 + l*128;   const float* bb2   = lnb2 + l*128;
    const short* m1Tl  = m1T + l*65536;  const float* m1bl  = m1b + l*512;
    const short* m2Tl  = m2T + l*65536;  const float* m2bl  = m2b + l*128;

    // guard red(=vtb) writes vs previous layer's MLP G1 reads
    __syncthreads();

    ln_sub(xr, g1, bb1, red, hb, wid, quad, l4);   // -> hb, trailing barrier

    // ---- QKV in two 32-row halves; j-loop unroll 2 = weight-load pipelining ----
    #pragma unroll 1
    for (int hh = 0; hh < 2; ++hh) {
      s8v af[2][4];
      #pragma unroll
      for (int m2 = 0; m2 < 2; ++m2)
        #pragma unroll
        for (int k0 = 0; k0 < 4; ++k0)
          af[m2][k0] = *(const s8v*)(hb + ((hh*2 + m2)*16 + l4)*136 + k0*32 + quad*8);
      __syncthreads();   // all waves hold this half's h rows; safe to overwrite

      #pragma unroll 2
      for (int j = 0; j < 6; ++j) {
        int col = wid*96 + j*16 + l4;
        s8v bf[4];
        #pragma unroll
        for (int k0 = 0; k0 < 4; ++k0)
          bf[k0] = *(const s8v*)(qkvTl + col*128 + k0*32 + quad*8);
        float bias = qkvbl[col];
        f4v acc[2];
        #pragma unroll
        for (int m2 = 0; m2 < 2; ++m2) { f4v bb = {bias,bias,bias,bias}; acc[m2] = bb; }
        #pragma unroll
        for (int k0 = 0; k0 < 4; ++k0)
          #pragma unroll
          for (int m2 = 0; m2 < 2; ++m2)
            acc[m2] = MFMA16(af[m2][k0], bf[k0], acc[m2]);
        if (col < 128) {
          #pragma unroll
          for (int m2 = 0; m2 < 2; ++m2)
            #pragma unroll
            for (int reg = 0; reg < 4; ++reg)
              hb[((hh*2+m2)*16 + quad*4 + reg)*136 + col] = (short)f2bf(acc[m2][reg] * ATT_SCALE);
        } else if (col < 256) {
          int c = col - 128;
          #pragma unroll
          for (int m2 = 0; m2 < 2; ++m2)
            #pragma unroll
            for (int reg = 0; reg < 4; ++reg)
              kb[((hh*2+m2)*16 + quad*4 + reg)*136 + c] = (short)f2bf(acc[m2][reg]);
        } else {
          int c = col - 256;
          #pragma unroll
          for (int m2 = 0; m2 < 2; ++m2)
            #pragma unroll
            for (int reg = 0; reg < 4; ++reg)
              vtb[c*72 + (hh*2+m2)*16 + quad*4 + reg] = (short)f2bf(acc[m2][reg]);
        }
      }
    }
    __syncthreads();

    // ---- attention: wave = head; zero internal barriers; two query-halves ----
    {
      const int h = wid;
      s8v bk[4];
      #pragma unroll
      for (int n2 = 0; n2 < 4; ++n2)
        bk[n2] = *(const s8v*)(kb + (n2*16 + l4)*136 + h*32 + quad*8);

      #pragma unroll 1
      for (int hh = 0; hh < 2; ++hh) {
        s8v aq[2];
        #pragma unroll
        for (int m2 = 0; m2 < 2; ++m2)
          aq[m2] = *(const s8v*)(hb + ((hh*2+m2)*16 + l4)*136 + h*32 + quad*8);
        f4v S[2][4];
        #pragma unroll
        for (int m2 = 0; m2 < 2; ++m2)
          #pragma unroll
          for (int n2 = 0; n2 < 4; ++n2) {
            f4v zz = {0.f,0.f,0.f,0.f};
            S[m2][n2] = MFMA16(aq[m2], bk[n2], zz);
          }

        #pragma unroll
        for (int m2 = 0; m2 < 2; ++m2)
          #pragma unroll
          for (int reg = 0; reg < 4; ++reg) {
            float mx = fmaxf(fmaxf(S[m2][0][reg], S[m2][1][reg]),
                             fmaxf(S[m2][2][reg], S[m2][3][reg]));
            mx = fmaxf(mx, __shfl_xor(mx, 1));
            mx = fmaxf(mx, __shfl_xor(mx, 2));
            mx = fmaxf(mx, __shfl_xor(mx, 4));
            mx = fmaxf(mx, __shfl_xor(mx, 8));
            float E = 0.f, W = 0.f;
            #pragma unroll
            for (int n2 = 0; n2 < 4; ++n2) {
              float e = __expf(S[m2][n2][reg] - mx);
              E += e; W += e * rv[n2];
              S[m2][n2][reg] = e * rv[n2];
            }
            E += __shfl_xor(E, 1); E += __shfl_xor(E, 2);
            E += __shfl_xor(E, 4); E += __shfl_xor(E, 8);
            W += __shfl_xor(W, 1); W += __shfl_xor(W, 2);
            W += __shfl_xor(W, 4); W += __shfl_xor(W, 8);
            float inv = __builtin_amdgcn_rcpf(W + 1e-9f * E);
            #pragma unroll
            for (int n2 = 0; n2 < 4; ++n2) S[m2][n2][reg] *= inv;
          }

        // PV in 32-key chunks; P transposed through own kb columns
        f4v o[2][2];
        #pragma unroll
        for (int m2 = 0; m2 < 2; ++m2)
          #pragma unroll
          for (int nt = 0; nt < 2; ++nt) { f4v zz = {0.f,0.f,0.f,0.f}; o[m2][nt] = zz; }
        #pragma unroll
        for (int c = 0; c < 2; ++c) {
          #pragma unroll
          for (int m2 = 0; m2 < 2; ++m2)
            #pragma unroll
            for (int n2 = 0; n2 < 2; ++n2)
              #pragma unroll
              for (int reg = 0; reg < 4; ++reg)
                kb[((hh*2+m2)*16 + quad*4 + reg)*136 + h*32 + n2*16 + l4] =
                    (short)f2bf(S[m2][2*c + n2][reg]);
          s8v ap[2];
          #pragma unroll
          for (int m2 = 0; m2 < 2; ++m2)
            ap[m2] = *(const s8v*)(kb + ((hh*2+m2)*16 + l4)*136 + h*32 + quad*8);
          #pragma unroll
          for (int nt = 0; nt < 2; ++nt) {
            s8v bv = *(const s8v*)(vtb + (h*32 + nt*16 + l4)*72 + c*32 + quad*8);
            #pragma unroll
            for (int m2 = 0; m2 < 2; ++m2)
              o[m2][nt] = MFMA16(ap[m2], bv, o[m2][nt]);
          }
        }
        #pragma unroll
        for (int m2 = 0; m2 < 2; ++m2)
          #pragma unroll
          for (int nt = 0; nt < 2; ++nt)
            #pragma unroll
            for (int reg = 0; reg < 4; ++reg)
              hb[((hh*2+m2)*16 + quad*4 + reg)*136 + h*32 + nt*16 + l4] =
                  (short)f2bf(o[m2][nt][reg]);
      }
    }
    __syncthreads();

    // ---- output proj + residual (xr-indexed: keep unrolled) ----
    #pragma unroll
    for (int hh = 0; hh < 2; ++hh) {
      s8v ao[2][4];
      #pragma unroll
      for (int m2 = 0; m2 < 2; ++m2)
        #pragma unroll
        for (int k0 = 0; k0 < 4; ++k0)
          ao[m2][k0] = *(const s8v*)(hb + ((hh*2+m2)*16 + l4)*136 + k0*32 + quad*8);
      #pragma unroll
      for (int nt = 0; nt < 2; ++nt) {
        int c = wid*32 + nt*16 + l4;
        s8v bo[4];
        #pragma unroll
        for (int k0 = 0; k0 < 4; ++k0)
          bo[k0] = *(const s8v*)(outTl + c*128 + k0*32 + quad*8);
        float bias = outbl[c];
        #pragma unroll
        for (int m2 = 0; m2 < 2; ++m2) {
          int mt = hh*2 + m2;
          f4v a2 = {xr[mt][nt][0] + bias, xr[mt][nt][1] + bias,
                    xr[mt][nt][2] + bias, xr[mt][nt][3] + bias};
          #pragma unroll
          for (int k0 = 0; k0 < 4; ++k0)
            a2 = MFMA16(ao[m2][k0], bo[k0], a2);
          #pragma unroll
          for (int reg = 0; reg < 4; ++reg)
            xr[mt][nt][reg] = a2[reg];
        }
      }
    }

    ln_sub(xr, g2, bb2, red, hb, wid, quad, l4);   // LN2 -> hb

    // ---- MLP: bm hoisted (was 2x per hh); b2f loaded before barrier ----
    #pragma unroll 1
    for (int cc = 0; cc < 4; ++cc) {
      short* G = (cc & 1) ? vtb : kb;
      s8v bm[2][4];
      float bias1[2];
      #pragma unroll
      for (int nt = 0; nt < 2; ++nt) {
        int jc = cc*128 + wid*32 + nt*16 + l4;
        #pragma unroll
        for (int k0 = 0; k0 < 4; ++k0)
          bm[nt][k0] = *(const s8v*)(m1Tl + jc*128 + k0*32 + quad*8);
        bias1[nt] = m1bl[jc];
      }
      #pragma unroll 1
      for (int hh = 0; hh < 2; ++hh) {
        s8v afm[2][4];
        #pragma unroll
        for (int m2 = 0; m2 < 2; ++m2)
          #pragma unroll
          for (int k0 = 0; k0 < 4; ++k0)
            afm[m2][k0] = *(const s8v*)(hb + ((hh*2+m2)*16 + l4)*136 + k0*32 + quad*8);
        #pragma unroll
        for (int nt = 0; nt < 2; ++nt) {
          #pragma unroll
          for (int m2 = 0; m2 < 2; ++m2) {
            f4v a2 = {bias1[nt], bias1[nt], bias1[nt], bias1[nt]};
            #pragma unroll
            for (int k0 = 0; k0 < 4; ++k0)
              a2 = MFMA16(afm[m2][k0], bm[nt][k0], a2);
            #pragma unroll
            for (int reg = 0; reg < 4; ++reg) {
              // gelu(v) = v * sigmoid(2*sqrt(2/pi)*(v + 0.044715 v^3))
              float v = a2[reg];
              float t = v * v;
              float u = fmaf(0.044715f, t, 1.0f);
              float w = v * u;
              float e = __expf(NGC2 * w);
              float gl = v * __builtin_amdgcn_rcpf(e + 1.0f);
              G[((hh*2+m2)*16 + quad*4 + reg)*136 + wid*32 + nt*16 + l4] = (short)f2bf(gl);
            }
          }
        }
      }
      // prefetch m2 weights BEFORE the barrier: L2 latency overlaps barrier wait
      s8v b2f[2][4];
      #pragma unroll
      for (int nt = 0; nt < 2; ++nt) {
        int c = wid*32 + nt*16 + l4;
        #pragma unroll
        for (int k0 = 0; k0 < 4; ++k0)
          b2f[nt][k0] = *(const s8v*)(m2Tl + c*512 + cc*128 + k0*32 + quad*8);
      }
      __syncthreads();
      #pragma unroll
      for (int hh = 0; hh < 2; ++hh) {
        s8v at4[2][4];
        #pragma unroll
        for (int m2 = 0; m2 < 2; ++m2)
          #pragma unroll
          for (int k0 = 0; k0 < 4; ++k0)
            at4[m2][k0] = *(const s8v*)(G + ((hh*2+m2)*16 + l4)*136 + k0*32 + quad*8);
        #pragma unroll
        for (int nt = 0; nt < 2; ++nt) {
          #pragma unroll
          for (int m2 = 0; m2 < 2; ++m2) {
            int mt = hh*2 + m2;
            f4v a2 = {xr[mt][nt][0], xr[mt][nt][1], xr[mt][nt][2], xr[mt][nt][3]};
            #pragma unroll
            for (int k0 = 0; k0 < 4; ++k0)
              a2 = MFMA16(at4[m2][k0], b2f[nt][k0], a2);
            #pragma unroll
            for (int reg = 0; reg < 4; ++reg)
              xr[mt][nt][reg] = a2[reg];
          }
        }
      }
    }
    #pragma unroll
    for (int nt = 0; nt < 2; ++nt) {
      float b = m2bl[wid*32 + nt*16 + l4];
      #pragma unroll
      for (int mt = 0; mt < 4; ++mt)
        #pragma unroll
        for (int reg = 0; reg < 4; ++reg)
          xr[mt][nt][reg] += b;
    }
  }

  #pragma unroll
  for (int mt = 0; mt < 4; ++mt)
    #pragma unroll
    for (int nt = 0; nt < 2; ++nt)
      #pragma unroll
      for (int reg = 0; reg < 4; ++reg)
        xg[(mt*16 + quad*4 + reg)*128 + wid*32 + nt*16 + l4] = (short)f2bf(xr[mt][nt][reg]);
}

// ---------------- gather + GNN linear (bf16 in/out) ----------------
__global__ __launch_bounds__(256) void k_gnn(
    const short* __restrict__ feat, const int* __restrict__ nef,
    const int* __restrict__ corr, const int* __restrict__ centers,
    const int* __restrict__ nef2, const short* __restrict__ gnnT,
    short* __restrict__ out) {
  __shared__ __align__(16) short Ab[64 * 264];
  int n = blockIdx.x, t = threadIdx.x;
  int wid = t >> 6, lane = t & 63, l4 = lane & 15, quad = lane >> 4;
  int j = t >> 2, qq = t & 3;
  int e  = iclamp(nef[n*64 + j], 0, N_EDGE - 1);
  int ce = iclamp(corr[e], 0, N_EDGE - 1);
  size_t r1 = ((size_t)iclamp(centers[e],  0, N_NODES-1) * 64 + iclamp(nef2[e],  0, 63)) * 128;
  size_t r2 = ((size_t)iclamp(centers[ce], 0, N_NODES-1) * 64 + iclamp(nef2[ce], 0, 63)) * 128;
  {
    const s8v* p1 = (const s8v*)(feat + r1 + qq*32);
    const s8v* p2 = (const s8v*)(feat + r2 + qq*32);
    #pragma unroll
    for (int ii = 0; ii < 4; ++ii) {
      *(s8v*)(Ab + j*264 + qq*32 + ii*8)       = p1[ii];
      *(s8v*)(Ab + j*264 + 128 + qq*32 + ii*8) = p2[ii];
    }
  }
  __syncthreads();
  f4v acc[4][2];
  #pragma unroll
  for (int mt = 0; mt < 4; ++mt)
    #pragma unroll
    for (int nt = 0; nt < 2; ++nt) { f4v zz = {0.f,0.f,0.f,0.f}; acc[mt][nt] = zz; }
  #pragma unroll
  for (int k0 = 0; k0 < 8; ++k0) {
    s8v a[4];
    #pragma unroll
    for (int mt = 0; mt < 4; ++mt)
      a[mt] = *(const s8v*)(Ab + (mt*16 + l4)*264 + k0*32 + quad*8);
    #pragma unroll
    for (int nt = 0; nt < 2; ++nt) {
      s8v b = *(const s8v*)(gnnT + (wid*32 + nt*16 + l4)*256 + k0*32 + quad*8);
      #pragma unroll
      for (int mt = 0; mt < 4; ++mt)
        acc[mt][nt] = MFMA16(a[mt], b, acc[mt][nt]);
    }
  }
  #pragma unroll
  for (int mt = 0; mt < 4; ++mt)
    #pragma unroll
    for (int nt = 0; nt < 2; ++nt)
      #pragma unroll
      for (int reg = 0; reg < 4; ++reg)
        out[((size_t)n*64 + mt*16 + quad*4 + reg)*128 + wid*32 + nt*16 + l4] =
            (short)f2bf(acc[mt][nt][reg]);
}

// ---------------- final masked sum + head ----------------
__global__ __launch_bounds__(256) void k_final(
    const short* __restrict__ feat, const short* __restrict__ buf2,
    const float* __restrict__ rm, const float* __restrict__ lastw,
    const float* __restrict__ compw, const int* __restrict__ species,
    float* __restrict__ out) {
  __shared__ float part[4];
  int n = blockIdx.x, t = threadIdx.x;
  int wid = t >> 6, lane = t & 63;
  int j = t >> 2, qq = t & 3;
  size_t base = ((size_t)n*64 + j)*128 + qq*32;
  float s = 0.f;
  #pragma unroll
  for (int i = 0; i < 32; ++i)
    s += (bf2f(feat[base + i]) + bf2f(buf2[base + i])) * lastw[qq*32 + i];
  s += __shfl_xor(s, 1);
  s += __shfl_xor(s, 2);
  float v = (qq == 0) ? s * rm[n*64 + j] : 0.f;
  v += __shfl_xor(v, 4);  v += __shfl_xor(v, 8);
  v += __shfl_xor(v, 16); v += __shfl_xor(v, 32);
  if (lane == 0) part[wid] = v;
  __syncthreads();
  if (t == 0) out[n] = part[0] + part[1] + part[2] + part[3]
                       + compw[iclamp(species[n], 0, 3)];
}

// ---------------- host ----------------

extern "C" void kernel_launch(void* const* d_in, const int* in_sizes, int n_in,
                              void* d_out, int out_size, void* d_ws, size_t ws_size,
                              hipStream_t stream) {
  const float* ev      = (const float*)d_in[0];
  const float* cart    = (const float*)d_in[1];
  const float* cemb    = (const float*)d_in[2];
  const float* nemb    = (const float*)d_in[3];
  const float* comp    = (const float*)d_in[4];
  const float* gnnw    = (const float*)d_in[5];
  const float* lastw   = (const float*)d_in[6];
  const float* compw   = (const float*)d_in[7];
  const int*   species = (const int*)d_in[8];
  const int*   centers = (const int*)d_in[9];
  const int*   neighbors = (const int*)d_in[10];
  const int*   nef     = (const int*)d_in[11];
  /* d_in[12] = nef_mask: unused (masked slots are provably inert) */
  const int*   nef2    = (const int*)d_in[13];
  const int*   corr    = (const int*)d_in[14];

  // workspace layout (bytes)
  const size_t OFF_RM   = 0;           // 1,048,576
  const size_t OFF_FEAT = 1048576;     // 67,108,864 (bf16)
  const size_t OFF_BUF2 = 68157440;    // 67,108,864 (bf16)
  const size_t OFF_TABS = 135266304;   // 5,632
  const size_t OFF_WBF  = 135271936;   // 1,638,400
  const size_t NEED     = 136910336;
  if (ws_size < NEED) return;  // insufficient scratch: fail cleanly, not a fault

  char* ws = (char*)d_ws;
  float* rm   = (float*)(ws + OFF_RM);
  short* feat = (short*)(ws + OFF_FEAT);
  short* buf2 = (short*)(ws + OFF_BUF2);
  float* tabs = (float*)(ws + OFF_TABS);
  short* wbf  = (short*)(ws + OFF_WBF);

  short* t0q  = wbf + 0;       // 2x(384x128)
  short* t0o  = wbf + 98304;   // 2x(128x128)
  short* t0m1 = wbf + 131072;  // 2x(512x128)
  short* t0m2 = wbf + 262144;  // 2x(128x512)
  short* t1q  = wbf + 393216;
  short* t1o  = wbf + 491520;
  short* t1m1 = wbf + 524288;
  short* t1m2 = wbf + 655360;
  short* gnnT = wbf + 786432;  // 128x256

  hipMemsetAsync(rm, 0, 4096*64*sizeof(float), stream);

  k_tr<<<384, 256, 0, stream>>>((const float*)d_in[17], t0q,  2, 128, 384);
  k_tr<<<128, 256, 0, stream>>>((const float*)d_in[19], t0o,  2, 128, 128);
  k_tr<<<512, 256, 0, stream>>>((const float*)d_in[23], t0m1, 2, 128, 512);
  k_tr<<<512, 256, 0, stream>>>((const float*)d_in[25], t0m2, 2, 512, 128);
  k_tr<<<384, 256, 0, stream>>>((const float*)d_in[29], t1q,  2, 128, 384);
  k_tr<<<128, 256, 0, stream>>>((const float*)d_in[31], t1o,  2, 128, 128);
  k_tr<<<512, 256, 0, stream>>>((const float*)d_in[35], t1m1, 2, 128, 512);
  k_tr<<<512, 256, 0, stream>>>((const float*)d_in[37], t1m2, 2, 512, 128);
  k_tr<<<128, 256, 0, stream>>>(gnnw, gnnT, 1, 256, 128);
  k_tabs<<<6, 256, 0, stream>>>(cart, cemb, nemb, comp, tabs);
  k_rm<<<512, 256, 0, stream>>>(ev, centers, nef2, rm);
  k_enc<<<4096, 256, 0, stream>>>(ev, nef, centers, neighbors, species, tabs, feat);

  k_tf<<<4096, 256, 0, stream>>>(feat, rm,
      (const float*)d_in[15], (const float*)d_in[16], t0q, (const float*)d_in[18],
      t0o, (const float*)d_in[20], (const float*)d_in[21], (const float*)d_in[22],
      t0m1, (const float*)d_in[24], t0m2, (const float*)d_in[26]);

  k_gnn<<<4096, 256, 0, stream>>>(feat, nef, corr, centers, nef2, gnnT, buf2);

  k_tf<<<4096, 256, 0, stream>>>(buf2, rm,
      (const float*)d_in[27], (const float*)d_in[28], t1q, (const float*)d_in[30],
      t1o, (const float*)d_in[32], (const float*)d_in[33], (const float*)d_in[34],
      t1m1, (const float*)d_in[36], t1m2, (const float*)d_in[38]);

  k_final<<<4096, 256, 0, stream>>>(feat, buf2, rm, lastw, compw, species, (float*)d_out);
}

// Round 9
// 1606.852 us; speedup vs baseline: 1.3211x; 1.0094x over previous
//
#include <hip/hip_runtime.h>

typedef short s8v __attribute__((ext_vector_type(8)));
typedef float f4v __attribute__((ext_vector_type(4)));

#define MFMA16(a,b,c) __builtin_amdgcn_mfma_f32_16x16x32_bf16((a),(b),(c),0,0,0)

#define N_NODES 4096
#define N_EDGE  131072
#define ATT_SCALE 0.17677669529663687f   // 1/sqrt(32)
#define NGC2     -1.5957691216057308f    // -2*sqrt(2/pi)

// fast path (hot kernel): round-half-up, 2 VALU
__device__ __forceinline__ unsigned short f2bf(float f) {
  union { float f; unsigned u; } v; v.f = f;
  return (unsigned short)((v.u + 0x8000u) >> 16);
}
// precise path (one-time prep): RNE
__device__ __forceinline__ unsigned short f2bf_rne(float f) {
  union { float f; unsigned u; } v; v.f = f;
  unsigned r = v.u + 0x7fffu + ((v.u >> 16) & 1u);
  return (unsigned short)(r >> 16);
}
__device__ __forceinline__ float bf2f(short s) {
  union { unsigned u; float f; } v;
  v.u = ((unsigned)(unsigned short)s) << 16;
  return v.f;
}
__device__ __forceinline__ int iclamp(int v, int lo, int hi) {
  return v < lo ? lo : (v > hi ? hi : v);
}

// ---------------- prep kernels ----------------

__global__ void k_tr(const float* __restrict__ src, short* __restrict__ dst,
                     int L, int K, int N) {
  int idx = blockIdx.x * 256 + threadIdx.x;
  int tot = L * K * N;
  if (idx >= tot) return;
  int l = idx / (K * N);
  int r = idx - l * (K * N);
  int k = r / N;
  int n = r - k * N;
  dst[l * K * N + n * K + k] = (short)f2bf_rne(src[idx]);
}

__global__ void k_tabs(const float* __restrict__ cart, const float* __restrict__ cemb,
                       const float* __restrict__ nemb, const float* __restrict__ comp,
                       float* __restrict__ tabs) {
  int idx = blockIdx.x * 256 + threadIdx.x;
  if (idx >= 1408) return;
  float s = 0.f;
  if (idx < 384) {
    int i = idx >> 7, d = idx & 127;
    for (int j = 0; j < 128; ++j) s += cart[i * 128 + j] * comp[j * 128 + d];
  } else if (idx < 896) {
    int i2 = idx - 384; int sp = i2 >> 7, d = i2 & 127;
    for (int j = 0; j < 128; ++j) s += cemb[sp * 128 + j] * comp[(128 + j) * 128 + d];
  } else {
    int i2 = idx - 896; int sp = i2 >> 7, d = i2 & 127;
    for (int j = 0; j < 128; ++j) s += nemb[sp * 128 + j] * comp[(256 + j) * 128 + d];
  }
  tabs[idx] = s;
}

__global__ void k_rm(const float* __restrict__ ev, const int* __restrict__ centers,
                     const int* __restrict__ nef2, float* __restrict__ rm) {
  int e = blockIdx.x * 256 + threadIdx.x;
  if (e >= N_EDGE) return;
  float x = ev[e*3], y = ev[e*3+1], z = ev[e*3+2];
  float r = sqrtf(x*x + y*y + z*z);
  float rad;
  if (r < 3.0f)      rad = 1.0f;
  else if (r < 5.0f) rad = 0.5f * (cosf(3.14159265358979f * (r - 3.0f) * 0.5f) + 1.0f);
  else               rad = 0.0f;
  int c  = iclamp(centers[e], 0, N_NODES - 1);
  int rk = iclamp(nef2[e], 0, 63);
  rm[c * 64 + rk] = rad;
}

__global__ __launch_bounds__(256) void k_enc(
    const float* __restrict__ ev, const int* __restrict__ nef,
    const int* __restrict__ centers, const int* __restrict__ neighbors,
    const int* __restrict__ species, const float* __restrict__ tabs,
    short* __restrict__ feat) {
  int n = blockIdx.x, t = threadIdx.x, j = t >> 2, qq = t & 3;
  int e = iclamp(nef[n * 64 + j], 0, N_EDGE - 1);
  float e0 = ev[e*3], e1 = ev[e*3+1], e2 = ev[e*3+2];
  int nc = iclamp(centers[e],   0, N_NODES - 1);
  int nn = iclamp(neighbors[e], 0, N_NODES - 1);
  int sc = iclamp(species[nc], 0, 3), sn = iclamp(species[nn], 0, 3);
  const float* m0 = tabs + qq*32;
  const float* m1 = tabs + 128 + qq*32;
  const float* m2 = tabs + 256 + qq*32;
  const float* tc = tabs + 384 + sc*128 + qq*32;
  const float* tn = tabs + 896 + sn*128 + qq*32;
  short* o = feat + ((size_t)(n*64 + j))*128 + qq*32;
  #pragma unroll
  for (int i = 0; i < 32; i += 2) {
    float a = e0*m0[i]   + e1*m1[i]   + e2*m2[i]   + tc[i]   + tn[i];
    float b = e0*m0[i+1] + e1*m1[i+1] + e2*m2[i+1] + tc[i+1] + tn[i+1];
    *(unsigned*)(o + i) = (unsigned)f2bf_rne(a) | ((unsigned)f2bf_rne(b) << 16);
  }
}

// ---------------- fused transformer (2 layers), static 52KB LDS ----------------
// block = one node; 4 waves partition columns. Residual x in f32 regs (AGPR-side),
// MFMA C-layout: row = mt*16+quad*4+reg, col = wid*32+nt*16+l4.
// LDS: hb (17408) | kb (17408) | vtb (18432, red 2048 aliased at its base).
// 53248*3 = 159744 <= 163840 -> LDS permits 3 blocks/CU.
// Register model (R2-R8): unified RF, (256,N) splits budget ~evenly arch/AGPR.
// (256,3) -> 84 arch + 84 AGPR. Halved phases + unroll-1 fences keep arch
// demand ~75-80 (frags 32+16 + addr ~20); accumulators S/o/xr (80 f32) live
// AGPR-side; small overshoot spills to FREE AGPRs (v_accvgpr, ~free) not
// scratch. R3/R4's scratch blowup came from unsplit phases (demand ~130).
// Falsifier: WRITE_SIZE >> 65MB means scratch spills -> revert to (256,2).

__device__ __forceinline__ void ln_sub(float (&xr)[4][2][4],
                                       const float* __restrict__ gw, const float* __restrict__ gb,
                                       float* red, short* hb, int wid, int quad, int l4) {
  #pragma unroll
  for (int mt = 0; mt < 4; ++mt)
    #pragma unroll
    for (int reg = 0; reg < 4; ++reg) {
      float a = xr[mt][0][reg] + xr[mt][1][reg];
      float s = xr[mt][0][reg]*xr[mt][0][reg] + xr[mt][1][reg]*xr[mt][1][reg];
      #pragma unroll
      for (int m = 1; m < 16; m <<= 1) { a += __shfl_xor(a, m); s += __shfl_xor(s, m); }
      if (l4 == 0) {
        int r = mt*16 + quad*4 + reg;
        red[(wid*64 + r)*2]     = a;
        red[(wid*64 + r)*2 + 1] = s;
      }
    }
  __syncthreads();
  int tid = threadIdx.x;
  if (tid < 64) {
    float a = 0.f, s = 0.f;
    #pragma unroll
    for (int w = 0; w < 4; ++w) { a += red[(w*64 + tid)*2]; s += red[(w*64 + tid)*2 + 1]; }
    float mean = a * (1.f/128.f);
    float var  = s * (1.f/128.f) - mean*mean;
    red[tid*2]     = mean;
    red[tid*2 + 1] = rsqrtf(var + 1e-5f);
  }
  __syncthreads();
  float gv[2], bv[2];
  #pragma unroll
  for (int nt = 0; nt < 2; ++nt) { int c = wid*32 + nt*16 + l4; gv[nt] = gw[c]; bv[nt] = gb[c]; }
  #pragma unroll
  for (int mt = 0; mt < 4; ++mt)
    #pragma unroll
    for (int reg = 0; reg < 4; ++reg) {
      int r = mt*16 + quad*4 + reg;
      float mean = red[r*2], inv = red[r*2 + 1];
      #pragma unroll
      for (int nt = 0; nt < 2; ++nt) {
        float h = (xr[mt][nt][reg] - mean) * inv * gv[nt] + bv[nt];
        hb[r*136 + wid*32 + nt*16 + l4] = (short)f2bf(h);
      }
    }
  __syncthreads();
}

__global__ __launch_bounds__(256, 3) void k_tf(
    short* __restrict__ x, const float* __restrict__ rm,
    const float* __restrict__ lnw1, const float* __restrict__ lnb1,
    const short* __restrict__ qkvT, const float* __restrict__ qkvb,
    const short* __restrict__ outT, const float* __restrict__ outb,
    const float* __restrict__ lnw2, const float* __restrict__ lnb2,
    const short* __restrict__ m1T, const float* __restrict__ m1b,
    const short* __restrict__ m2T, const float* __restrict__ m2b) {
  __shared__ __align__(16) char smem[53248];
  short* hb  = (short*)smem;              // 17408 B: LN-out / q / attn-out
  short* kb  = (short*)(smem + 17408);    // 17408 B: k ; P-scratch (own cols); MLP G0
  short* vtb = (short*)(smem + 34816);    // 18432 B: V^T [feat128][key stride 72]; MLP G1
  float* red = (float*)(smem + 34816);    // 2048 B aliased at vtb base (LN phases only)

  const int tid = threadIdx.x;
  const int wid = tid >> 6;
  const int lane = tid & 63;
  const int l4 = lane & 15;
  const int quad = lane >> 4;
  const int n = blockIdx.x;

  float rv[4];
  #pragma unroll
  for (int n2 = 0; n2 < 4; ++n2) rv[n2] = rm[n*64 + n2*16 + l4];

  short* xg = x + (size_t)n * 64 * 128;
  float xr[4][2][4];
  #pragma unroll
  for (int mt = 0; mt < 4; ++mt)
    #pragma unroll
    for (int nt = 0; nt < 2; ++nt)
      #pragma unroll
      for (int reg = 0; reg < 4; ++reg)
        xr[mt][nt][reg] = bf2f(xg[(mt*16 + quad*4 + reg)*128 + wid*32 + nt*16 + l4]);

  for (int l = 0; l < 2; ++l) {
    const float* g1    = lnw1 + l*128;   const float* bb1   = lnb1 + l*128;
    const short* qkvTl = qkvT + l*49152; const float* qkvbl = qkvb + l*384;
    const short* outTl = outT + l*16384; const float* outbl = outb + l*128;
    const float* g2    = lnw2 + l*128;   const float* bb2   = lnb2 + l*128;
    const short* m1Tl  = m1T + l*65536;  const float* m1bl  = m1b + l*512;
    const short* m2Tl  = m2T + l*65536;  const float* m2bl  = m2b + l*128;

    // guard red(=vtb) writes vs previous layer's MLP G1 reads
    __syncthreads();

    ln_sub(xr, g1, bb1, red, hb, wid, quad, l4);   // -> hb, trailing barrier

    // ---- QKV in two 32-row halves; unroll-1 fences cap register pressure ----
    #pragma unroll 1
    for (int hh = 0; hh < 2; ++hh) {
      s8v af[2][4];
      #pragma unroll
      for (int m2 = 0; m2 < 2; ++m2)
        #pragma unroll
        for (int k0 = 0; k0 < 4; ++k0)
          af[m2][k0] = *(const s8v*)(hb + ((hh*2 + m2)*16 + l4)*136 + k0*32 + quad*8);
      __syncthreads();   // all waves hold this half's h rows; safe to overwrite

      #pragma unroll 1
      for (int j = 0; j < 6; ++j) {
        int col = wid*96 + j*16 + l4;
        s8v bf[4];
        #pragma unroll
        for (int k0 = 0; k0 < 4; ++k0)
          bf[k0] = *(const s8v*)(qkvTl + col*128 + k0*32 + quad*8);
        float bias = qkvbl[col];
        f4v acc[2];
        #pragma unroll
        for (int m2 = 0; m2 < 2; ++m2) { f4v bb = {bias,bias,bias,bias}; acc[m2] = bb; }
        #pragma unroll
        for (int k0 = 0; k0 < 4; ++k0)
          #pragma unroll
          for (int m2 = 0; m2 < 2; ++m2)
            acc[m2] = MFMA16(af[m2][k0], bf[k0], acc[m2]);
        if (col < 128) {
          #pragma unroll
          for (int m2 = 0; m2 < 2; ++m2)
            #pragma unroll
            for (int reg = 0; reg < 4; ++reg)
              hb[((hh*2+m2)*16 + quad*4 + reg)*136 + col] = (short)f2bf(acc[m2][reg] * ATT_SCALE);
        } else if (col < 256) {
          int c = col - 128;
          #pragma unroll
          for (int m2 = 0; m2 < 2; ++m2)
            #pragma unroll
            for (int reg = 0; reg < 4; ++reg)
              kb[((hh*2+m2)*16 + quad*4 + reg)*136 + c] = (short)f2bf(acc[m2][reg]);
        } else {
          int c = col - 256;
          #pragma unroll
          for (int m2 = 0; m2 < 2; ++m2)
            #pragma unroll
            for (int reg = 0; reg < 4; ++reg)
              vtb[c*72 + (hh*2+m2)*16 + quad*4 + reg] = (short)f2bf(acc[m2][reg]);
        }
      }
    }
    __syncthreads();

    // ---- attention: wave = head; zero internal barriers; two query-halves ----
    {
      const int h = wid;
      s8v bk[4];
      #pragma unroll
      for (int n2 = 0; n2 < 4; ++n2)
        bk[n2] = *(const s8v*)(kb + (n2*16 + l4)*136 + h*32 + quad*8);

      #pragma unroll 1
      for (int hh = 0; hh < 2; ++hh) {
        s8v aq[2];
        #pragma unroll
        for (int m2 = 0; m2 < 2; ++m2)
          aq[m2] = *(const s8v*)(hb + ((hh*2+m2)*16 + l4)*136 + h*32 + quad*8);
        f4v S[2][4];
        #pragma unroll
        for (int m2 = 0; m2 < 2; ++m2)
          #pragma unroll
          for (int n2 = 0; n2 < 4; ++n2) {
            f4v zz = {0.f,0.f,0.f,0.f};
            S[m2][n2] = MFMA16(aq[m2], bk[n2], zz);
          }

        #pragma unroll
        for (int m2 = 0; m2 < 2; ++m2)
          #pragma unroll
          for (int reg = 0; reg < 4; ++reg) {
            float mx = fmaxf(fmaxf(S[m2][0][reg], S[m2][1][reg]),
                             fmaxf(S[m2][2][reg], S[m2][3][reg]));
            mx = fmaxf(mx, __shfl_xor(mx, 1));
            mx = fmaxf(mx, __shfl_xor(mx, 2));
            mx = fmaxf(mx, __shfl_xor(mx, 4));
            mx = fmaxf(mx, __shfl_xor(mx, 8));
            float E = 0.f, W = 0.f;
            #pragma unroll
            for (int n2 = 0; n2 < 4; ++n2) {
              float e = __expf(S[m2][n2][reg] - mx);
              E += e; W += e * rv[n2];
              S[m2][n2][reg] = e * rv[n2];
            }
            E += __shfl_xor(E, 1); E += __shfl_xor(E, 2);
            E += __shfl_xor(E, 4); E += __shfl_xor(E, 8);
            W += __shfl_xor(W, 1); W += __shfl_xor(W, 2);
            W += __shfl_xor(W, 4); W += __shfl_xor(W, 8);
            float inv = __builtin_amdgcn_rcpf(W + 1e-9f * E);
            #pragma unroll
            for (int n2 = 0; n2 < 4; ++n2) S[m2][n2][reg] *= inv;
          }

        // PV in 32-key chunks; P transposed through own kb columns
        f4v o[2][2];
        #pragma unroll
        for (int m2 = 0; m2 < 2; ++m2)
          #pragma unroll
          for (int nt = 0; nt < 2; ++nt) { f4v zz = {0.f,0.f,0.f,0.f}; o[m2][nt] = zz; }
        #pragma unroll
        for (int c = 0; c < 2; ++c) {
          #pragma unroll
          for (int m2 = 0; m2 < 2; ++m2)
            #pragma unroll
            for (int n2 = 0; n2 < 2; ++n2)
              #pragma unroll
              for (int reg = 0; reg < 4; ++reg)
                kb[((hh*2+m2)*16 + quad*4 + reg)*136 + h*32 + n2*16 + l4] =
                    (short)f2bf(S[m2][2*c + n2][reg]);
          s8v ap[2];
          #pragma unroll
          for (int m2 = 0; m2 < 2; ++m2)
            ap[m2] = *(const s8v*)(kb + ((hh*2+m2)*16 + l4)*136 + h*32 + quad*8);
          #pragma unroll
          for (int nt = 0; nt < 2; ++nt) {
            s8v bv = *(const s8v*)(vtb + (h*32 + nt*16 + l4)*72 + c*32 + quad*8);
            #pragma unroll
            for (int m2 = 0; m2 < 2; ++m2)
              o[m2][nt] = MFMA16(ap[m2], bv, o[m2][nt]);
          }
        }
        #pragma unroll
        for (int m2 = 0; m2 < 2; ++m2)
          #pragma unroll
          for (int nt = 0; nt < 2; ++nt)
            #pragma unroll
            for (int reg = 0; reg < 4; ++reg)
              hb[((hh*2+m2)*16 + quad*4 + reg)*136 + h*32 + nt*16 + l4] =
                  (short)f2bf(o[m2][nt][reg]);
      }
    }
    __syncthreads();

    // ---- output proj + residual (xr-indexed: keep unrolled) ----
    #pragma unroll
    for (int hh = 0; hh < 2; ++hh) {
      s8v ao[2][4];
      #pragma unroll
      for (int m2 = 0; m2 < 2; ++m2)
        #pragma unroll
        for (int k0 = 0; k0 < 4; ++k0)
          ao[m2][k0] = *(const s8v*)(hb + ((hh*2+m2)*16 + l4)*136 + k0*32 + quad*8);
      #pragma unroll
      for (int nt = 0; nt < 2; ++nt) {
        int c = wid*32 + nt*16 + l4;
        s8v bo[4];
        #pragma unroll
        for (int k0 = 0; k0 < 4; ++k0)
          bo[k0] = *(const s8v*)(outTl + c*128 + k0*32 + quad*8);
        float bias = outbl[c];
        #pragma unroll
        for (int m2 = 0; m2 < 2; ++m2) {
          int mt = hh*2 + m2;
          f4v a2 = {xr[mt][nt][0] + bias, xr[mt][nt][1] + bias,
                    xr[mt][nt][2] + bias, xr[mt][nt][3] + bias};
          #pragma unroll
          for (int k0 = 0; k0 < 4; ++k0)
            a2 = MFMA16(ao[m2][k0], bo[k0], a2);
          #pragma unroll
          for (int reg = 0; reg < 4; ++reg)
            xr[mt][nt][reg] = a2[reg];
        }
      }
    }

    ln_sub(xr, g2, bb2, red, hb, wid, quad, l4);   // LN2 -> hb

    // ---- MLP: weights loaded inside nt loops to cap arch pressure at ~80 ----
    #pragma unroll 1
    for (int cc = 0; cc < 4; ++cc) {
      short* G = (cc & 1) ? vtb : kb;
      #pragma unroll 1
      for (int hh = 0; hh < 2; ++hh) {
        s8v afm[2][4];
        #pragma unroll
        for (int m2 = 0; m2 < 2; ++m2)
          #pragma unroll
          for (int k0 = 0; k0 < 4; ++k0)
            afm[m2][k0] = *(const s8v*)(hb + ((hh*2+m2)*16 + l4)*136 + k0*32 + quad*8);
        #pragma unroll
        for (int nt = 0; nt < 2; ++nt) {
          int jc = cc*128 + wid*32 + nt*16 + l4;
          s8v bm[4];
          #pragma unroll
          for (int k0 = 0; k0 < 4; ++k0)
            bm[k0] = *(const s8v*)(m1Tl + jc*128 + k0*32 + quad*8);
          float bias = m1bl[jc];
          #pragma unroll
          for (int m2 = 0; m2 < 2; ++m2) {
            f4v a2 = {bias, bias, bias, bias};
            #pragma unroll
            for (int k0 = 0; k0 < 4; ++k0)
              a2 = MFMA16(afm[m2][k0], bm[k0], a2);
            #pragma unroll
            for (int reg = 0; reg < 4; ++reg) {
              // gelu(v) = v * sigmoid(2*sqrt(2/pi)*(v + 0.044715 v^3))
              float v = a2[reg];
              float t = v * v;
              float u = fmaf(0.044715f, t, 1.0f);
              float w = v * u;
              float e = __expf(NGC2 * w);
              float gl = v * __builtin_amdgcn_rcpf(e + 1.0f);
              G[((hh*2+m2)*16 + quad*4 + reg)*136 + wid*32 + nt*16 + l4] = (short)f2bf(gl);
            }
          }
        }
      }
      __syncthreads();
      #pragma unroll
      for (int hh = 0; hh < 2; ++hh) {
        s8v at4[2][4];
        #pragma unroll
        for (int m2 = 0; m2 < 2; ++m2)
          #pragma unroll
          for (int k0 = 0; k0 < 4; ++k0)
            at4[m2][k0] = *(const s8v*)(G + ((hh*2+m2)*16 + l4)*136 + k0*32 + quad*8);
        #pragma unroll
        for (int nt = 0; nt < 2; ++nt) {
          int c = wid*32 + nt*16 + l4;
          s8v b2f[4];
          #pragma unroll
          for (int k0 = 0; k0 < 4; ++k0)
            b2f[k0] = *(const s8v*)(m2Tl + c*512 + cc*128 + k0*32 + quad*8);
          #pragma unroll
          for (int m2 = 0; m2 < 2; ++m2) {
            int mt = hh*2 + m2;
            f4v a2 = {xr[mt][nt][0], xr[mt][nt][1], xr[mt][nt][2], xr[mt][nt][3]};
            #pragma unroll
            for (int k0 = 0; k0 < 4; ++k0)
              a2 = MFMA16(at4[m2][k0], b2f[k0], a2);
            #pragma unroll
            for (int reg = 0; reg < 4; ++reg)
              xr[mt][nt][reg] = a2[reg];
          }
        }
      }
    }
    #pragma unroll
    for (int nt = 0; nt < 2; ++nt) {
      float b = m2bl[wid*32 + nt*16 + l4];
      #pragma unroll
      for (int mt = 0; mt < 4; ++mt)
        #pragma unroll
        for (int reg = 0; reg < 4; ++reg)
          xr[mt][nt][reg] += b;
    }
  }

  #pragma unroll
  for (int mt = 0; mt < 4; ++mt)
    #pragma unroll
    for (int nt = 0; nt < 2; ++nt)
      #pragma unroll
      for (int reg = 0; reg < 4; ++reg)
        xg[(mt*16 + quad*4 + reg)*128 + wid*32 + nt*16 + l4] = (short)f2bf(xr[mt][nt][reg]);
}

// ---------------- gather + GNN linear (bf16 in/out) ----------------
__global__ __launch_bounds__(256) void k_gnn(
    const short* __restrict__ feat, const int* __restrict__ nef,
    const int* __restrict__ corr, const int* __restrict__ centers,
    const int* __restrict__ nef2, const short* __restrict__ gnnT,
    short* __restrict__ out) {
  __shared__ __align__(16) short Ab[64 * 264];
  int n = blockIdx.x, t = threadIdx.x;
  int wid = t >> 6, lane = t & 63, l4 = lane & 15, quad = lane >> 4;
  int j = t >> 2, qq = t & 3;
  int e  = iclamp(nef[n*64 + j], 0, N_EDGE - 1);
  int ce = iclamp(corr[e], 0, N_EDGE - 1);
  size_t r1 = ((size_t)iclamp(centers[e],  0, N_NODES-1) * 64 + iclamp(nef2[e],  0, 63)) * 128;
  size_t r2 = ((size_t)iclamp(centers[ce], 0, N_NODES-1) * 64 + iclamp(nef2[ce], 0, 63)) * 128;
  {
    const s8v* p1 = (const s8v*)(feat + r1 + qq*32);
    const s8v* p2 = (const s8v*)(feat + r2 + qq*32);
    #pragma unroll
    for (int ii = 0; ii < 4; ++ii) {
      *(s8v*)(Ab + j*264 + qq*32 + ii*8)       = p1[ii];
      *(s8v*)(Ab + j*264 + 128 + qq*32 + ii*8) = p2[ii];
    }
  }
  __syncthreads();
  f4v acc[4][2];
  #pragma unroll
  for (int mt = 0; mt < 4; ++mt)
    #pragma unroll
    for (int nt = 0; nt < 2; ++nt) { f4v zz = {0.f,0.f,0.f,0.f}; acc[mt][nt] = zz; }
  #pragma unroll
  for (int k0 = 0; k0 < 8; ++k0) {
    s8v a[4];
    #pragma unroll
    for (int mt = 0; mt < 4; ++mt)
      a[mt] = *(const s8v*)(Ab + (mt*16 + l4)*264 + k0*32 + quad*8);
    #pragma unroll
    for (int nt = 0; nt < 2; ++nt) {
      s8v b = *(const s8v*)(gnnT + (wid*32 + nt*16 + l4)*256 + k0*32 + quad*8);
      #pragma unroll
      for (int mt = 0; mt < 4; ++mt)
        acc[mt][nt] = MFMA16(a[mt], b, acc[mt][nt]);
    }
  }
  #pragma unroll
  for (int mt = 0; mt < 4; ++mt)
    #pragma unroll
    for (int nt = 0; nt < 2; ++nt)
      #pragma unroll
      for (int reg = 0; reg < 4; ++reg)
        out[((size_t)n*64 + mt*16 + quad*4 + reg)*128 + wid*32 + nt*16 + l4] =
            (short)f2bf(acc[mt][nt][reg]);
}

// ---------------- final masked sum + head ----------------
__global__ __launch_bounds__(256) void k_final(
    const short* __restrict__ feat, const short* __restrict__ buf2,
    const float* __restrict__ rm, const float* __restrict__ lastw,
    const float* __restrict__ compw, const int* __restrict__ species,
    float* __restrict__ out) {
  __shared__ float part[4];
  int n = blockIdx.x, t = threadIdx.x;
  int wid = t >> 6, lane = t & 63;
  int j = t >> 2, qq = t & 3;
  size_t base = ((size_t)n*64 + j)*128 + qq*32;
  float s = 0.f;
  #pragma unroll
  for (int i = 0; i < 32; ++i)
    s += (bf2f(feat[base + i]) + bf2f(buf2[base + i])) * lastw[qq*32 + i];
  s += __shfl_xor(s, 1);
  s += __shfl_xor(s, 2);
  float v = (qq == 0) ? s * rm[n*64 + j] : 0.f;
  v += __shfl_xor(v, 4);  v += __shfl_xor(v, 8);
  v += __shfl_xor(v, 16); v += __shfl_xor(v, 32);
  if (lane == 0) part[wid] = v;
  __syncthreads();
  if (t == 0) out[n] = part[0] + part[1] + part[2] + part[3]
                       + compw[iclamp(species[n], 0, 3)];
}

// ---------------- host ----------------

extern "C" void kernel_launch(void* const* d_in, const int* in_sizes, int n_in,
                              void* d_out, int out_size, void* d_ws, size_t ws_size,
                              hipStream_t stream) {
  const float* ev      = (const float*)d_in[0];
  const float* cart    = (const float*)d_in[1];
  const float* cemb    = (const float*)d_in[2];
  const float* nemb    = (const float*)d_in[3];
  const float* comp    = (const float*)d_in[4];
  const float* gnnw    = (const float*)d_in[5];
  const float* lastw   = (const float*)d_in[6];
  const float* compw   = (const float*)d_in[7];
  const int*   species = (const int*)d_in[8];
  const int*   centers = (const int*)d_in[9];
  const int*   neighbors = (const int*)d_in[10];
  const int*   nef     = (const int*)d_in[11];
  /* d_in[12] = nef_mask: unused (masked slots are provably inert) */
  const int*   nef2    = (const int*)d_in[13];
  const int*   corr    = (const int*)d_in[14];

  // workspace layout (bytes)
  const size_t OFF_RM   = 0;           // 1,048,576
  const size_t OFF_FEAT = 1048576;     // 67,108,864 (bf16)
  const size_t OFF_BUF2 = 68157440;    // 67,108,864 (bf16)
  const size_t OFF_TABS = 135266304;   // 5,632
  const size_t OFF_WBF  = 135271936;   // 1,638,400
  const size_t NEED     = 136910336;
  if (ws_size < NEED) return;  // insufficient scratch: fail cleanly, not a fault

  char* ws = (char*)d_ws;
  float* rm   = (float*)(ws + OFF_RM);
  short* feat = (short*)(ws + OFF_FEAT);
  short* buf2 = (short*)(ws + OFF_BUF2);
  float* tabs = (float*)(ws + OFF_TABS);
  short* wbf  = (short*)(ws + OFF_WBF);

  short* t0q  = wbf + 0;       // 2x(384x128)
  short* t0o  = wbf + 98304;   // 2x(128x128)
  short* t0m1 = wbf + 131072;  // 2x(512x128)
  short* t0m2 = wbf + 262144;  // 2x(128x512)
  short* t1q  = wbf + 393216;
  short* t1o  = wbf + 491520;
  short* t1m1 = wbf + 524288;
  short* t1m2 = wbf + 655360;
  short* gnnT = wbf + 786432;  // 128x256

  hipMemsetAsync(rm, 0, 4096*64*sizeof(float), stream);

  k_tr<<<384, 256, 0, stream>>>((const float*)d_in[17], t0q,  2, 128, 384);
  k_tr<<<128, 256, 0, stream>>>((const float*)d_in[19], t0o,  2, 128, 128);
  k_tr<<<512, 256, 0, stream>>>((const float*)d_in[23], t0m1, 2, 128, 512);
  k_tr<<<512, 256, 0, stream>>>((const float*)d_in[25], t0m2, 2, 512, 128);
  k_tr<<<384, 256, 0, stream>>>((const float*)d_in[29], t1q,  2, 128, 384);
  k_tr<<<128, 256, 0, stream>>>((const float*)d_in[31], t1o,  2, 128, 128);
  k_tr<<<512, 256, 0, stream>>>((const float*)d_in[35], t1m1, 2, 128, 512);
  k_tr<<<512, 256, 0, stream>>>((const float*)d_in[37], t1m2, 2, 512, 128);
  k_tr<<<128, 256, 0, stream>>>(gnnw, gnnT, 1, 256, 128);
  k_tabs<<<6, 256, 0, stream>>>(cart, cemb, nemb, comp, tabs);
  k_rm<<<512, 256, 0, stream>>>(ev, centers, nef2, rm);
  k_enc<<<4096, 256, 0, stream>>>(ev, nef, centers, neighbors, species, tabs, feat);

  k_tf<<<4096, 256, 0, stream>>>(feat, rm,
      (const float*)d_in[15], (const float*)d_in[16], t0q, (const float*)d_in[18],
      t0o, (const float*)d_in[20], (const float*)d_in[21], (const float*)d_in[22],
      t0m1, (const float*)d_in[24], t0m2, (const float*)d_in[26]);

  k_gnn<<<4096, 256, 0, stream>>>(feat, nef, corr, centers, nef2, gnnT, buf2);

  k_tf<<<4096, 256, 0, stream>>>(buf2, rm,
      (const float*)d_in[27], (const float*)d_in[28], t1q, (const float*)d_in[30],
      t1o, (const float*)d_in[32], (const float*)d_in[33], (const float*)d_in[34],
      t1m1, (const float*)d_in[36], t1m2, (const float*)d_in[38]);

  k_final<<<4096, 256, 0, stream>>>(feat, buf2, rm, lastw, compw, species, (float*)d_out);
}

// Round 10
// 1602.415 us; speedup vs baseline: 1.3248x; 1.0028x over previous
//
#include <hip/hip_runtime.h>

typedef short s8v __attribute__((ext_vector_type(8)));
typedef float f4v __attribute__((ext_vector_type(4)));

#define MFMA16(a,b,c) __builtin_amdgcn_mfma_f32_16x16x32_bf16((a),(b),(c),0,0,0)

#define N_NODES 4096
#define N_EDGE  131072
#define ATT_SCALE 0.17677669529663687f   // 1/sqrt(32)
#define NGC2     -1.5957691216057308f    // -2*sqrt(2/pi)

// fast path (hot kernel): round-half-up, 2 VALU
__device__ __forceinline__ unsigned short f2bf(float f) {
  union { float f; unsigned u; } v; v.f = f;
  return (unsigned short)((v.u + 0x8000u) >> 16);
}
// precise path (one-time prep): RNE
__device__ __forceinline__ unsigned short f2bf_rne(float f) {
  union { float f; unsigned u; } v; v.f = f;
  unsigned r = v.u + 0x7fffu + ((v.u >> 16) & 1u);
  return (unsigned short)(r >> 16);
}
__device__ __forceinline__ float bf2f(short s) {
  union { unsigned u; float f; } v;
  v.u = ((unsigned)(unsigned short)s) << 16;
  return v.f;
}
__device__ __forceinline__ int iclamp(int v, int lo, int hi) {
  return v < lo ? lo : (v > hi ? hi : v);
}

// ---------------- prep kernels ----------------

__global__ void k_tr(const float* __restrict__ src, short* __restrict__ dst,
                     int L, int K, int N) {
  int idx = blockIdx.x * 256 + threadIdx.x;
  int tot = L * K * N;
  if (idx >= tot) return;
  int l = idx / (K * N);
  int r = idx - l * (K * N);
  int k = r / N;
  int n = r - k * N;
  dst[l * K * N + n * K + k] = (short)f2bf_rne(src[idx]);
}

__global__ void k_tabs(const float* __restrict__ cart, const float* __restrict__ cemb,
                       const float* __restrict__ nemb, const float* __restrict__ comp,
                       float* __restrict__ tabs) {
  int idx = blockIdx.x * 256 + threadIdx.x;
  if (idx >= 1408) return;
  float s = 0.f;
  if (idx < 384) {
    int i = idx >> 7, d = idx & 127;
    for (int j = 0; j < 128; ++j) s += cart[i * 128 + j] * comp[j * 128 + d];
  } else if (idx < 896) {
    int i2 = idx - 384; int sp = i2 >> 7, d = i2 & 127;
    for (int j = 0; j < 128; ++j) s += cemb[sp * 128 + j] * comp[(128 + j) * 128 + d];
  } else {
    int i2 = idx - 896; int sp = i2 >> 7, d = i2 & 127;
    for (int j = 0; j < 128; ++j) s += nemb[sp * 128 + j] * comp[(256 + j) * 128 + d];
  }
  tabs[idx] = s;
}

__global__ void k_rm(const float* __restrict__ ev, const int* __restrict__ centers,
                     const int* __restrict__ nef2, float* __restrict__ rm) {
  int e = blockIdx.x * 256 + threadIdx.x;
  if (e >= N_EDGE) return;
  float x = ev[e*3], y = ev[e*3+1], z = ev[e*3+2];
  float r = sqrtf(x*x + y*y + z*z);
  float rad;
  if (r < 3.0f)      rad = 1.0f;
  else if (r < 5.0f) rad = 0.5f * (cosf(3.14159265358979f * (r - 3.0f) * 0.5f) + 1.0f);
  else               rad = 0.0f;
  int c  = iclamp(centers[e], 0, N_NODES - 1);
  int rk = iclamp(nef2[e], 0, 63);
  rm[c * 64 + rk] = rad;
}

__global__ __launch_bounds__(256) void k_enc(
    const float* __restrict__ ev, const int* __restrict__ nef,
    const int* __restrict__ centers, const int* __restrict__ neighbors,
    const int* __restrict__ species, const float* __restrict__ tabs,
    short* __restrict__ feat) {
  int n = blockIdx.x, t = threadIdx.x, j = t >> 2, qq = t & 3;
  int e = iclamp(nef[n * 64 + j], 0, N_EDGE - 1);
  float e0 = ev[e*3], e1 = ev[e*3+1], e2 = ev[e*3+2];
  int nc = iclamp(centers[e],   0, N_NODES - 1);
  int nn = iclamp(neighbors[e], 0, N_NODES - 1);
  int sc = iclamp(species[nc], 0, 3), sn = iclamp(species[nn], 0, 3);
  const float* m0 = tabs + qq*32;
  const float* m1 = tabs + 128 + qq*32;
  const float* m2 = tabs + 256 + qq*32;
  const float* tc = tabs + 384 + sc*128 + qq*32;
  const float* tn = tabs + 896 + sn*128 + qq*32;
  short* o = feat + ((size_t)(n*64 + j))*128 + qq*32;
  #pragma unroll
  for (int i = 0; i < 32; i += 2) {
    float a = e0*m0[i]   + e1*m1[i]   + e2*m2[i]   + tc[i]   + tn[i];
    float b = e0*m0[i+1] + e1*m1[i+1] + e2*m2[i+1] + tc[i+1] + tn[i+1];
    *(unsigned*)(o + i) = (unsigned)f2bf_rne(a) | ((unsigned)f2bf_rne(b) << 16);
  }
}

// ---------------- fused transformer (2 layers), static 52KB LDS ----------------
// block = one node; 4 waves partition columns. Residual x in f32 regs (AGPR-side),
// MFMA C-layout: row = mt*16+quad*4+reg, col = wid*32+nt*16+l4.
// LDS: hb (17408) | kb (17408) | vtb (18432, red 2048 aliased at its base).
// 53248*3 <= 160KB -> 3 blocks/CU at (256,3): 84 arch + 84 AGPR per wave.
// R9: spill traffic 290MB at (256,3) localized to softmax (S 32 arch + bk 16
// held across hh + aq + temps). R10 trims the softmax arch peak:
//  - P-transpose scratch moved kb -> hb (own q cols, rows of current hh; q is
//    consumed into aq first; in-wave LDS ordering covers P/output overlap)
//  - kb therefore stays intact through attention -> bk reloaded per hh (16
//    regs freed during softmax)
//  - rv loaded inside the attention block (shorter live range)
// Falsifier: if WRITE_SIZE stays ~254MB or dur within 2% of 712us, the
// latency plateau is structural (LDS >= ~48KB irreducible; arch live ~100 vs
// 84@3blk / 128@2blk) -> declare roofline.

__device__ __forceinline__ void ln_sub(float (&xr)[4][2][4],
                                       const float* __restrict__ gw, const float* __restrict__ gb,
                                       float* red, short* hb, int wid, int quad, int l4) {
  #pragma unroll
  for (int mt = 0; mt < 4; ++mt)
    #pragma unroll
    for (int reg = 0; reg < 4; ++reg) {
      float a = xr[mt][0][reg] + xr[mt][1][reg];
      float s = xr[mt][0][reg]*xr[mt][0][reg] + xr[mt][1][reg]*xr[mt][1][reg];
      #pragma unroll
      for (int m = 1; m < 16; m <<= 1) { a += __shfl_xor(a, m); s += __shfl_xor(s, m); }
      if (l4 == 0) {
        int r = mt*16 + quad*4 + reg;
        red[(wid*64 + r)*2]     = a;
        red[(wid*64 + r)*2 + 1] = s;
      }
    }
  __syncthreads();
  int tid = threadIdx.x;
  if (tid < 64) {
    float a = 0.f, s = 0.f;
    #pragma unroll
    for (int w = 0; w < 4; ++w) { a += red[(w*64 + tid)*2]; s += red[(w*64 + tid)*2 + 1]; }
    float mean = a * (1.f/128.f);
    float var  = s * (1.f/128.f) - mean*mean;
    red[tid*2]     = mean;
    red[tid*2 + 1] = rsqrtf(var + 1e-5f);
  }
  __syncthreads();
  float gv[2], bv[2];
  #pragma unroll
  for (int nt = 0; nt < 2; ++nt) { int c = wid*32 + nt*16 + l4; gv[nt] = gw[c]; bv[nt] = gb[c]; }
  #pragma unroll
  for (int mt = 0; mt < 4; ++mt)
    #pragma unroll
    for (int reg = 0; reg < 4; ++reg) {
      int r = mt*16 + quad*4 + reg;
      float mean = red[r*2], inv = red[r*2 + 1];
      #pragma unroll
      for (int nt = 0; nt < 2; ++nt) {
        float h = (xr[mt][nt][reg] - mean) * inv * gv[nt] + bv[nt];
        hb[r*136 + wid*32 + nt*16 + l4] = (short)f2bf(h);
      }
    }
  __syncthreads();
}

__global__ __launch_bounds__(256, 3) void k_tf(
    short* __restrict__ x, const float* __restrict__ rm,
    const float* __restrict__ lnw1, const float* __restrict__ lnb1,
    const short* __restrict__ qkvT, const float* __restrict__ qkvb,
    const short* __restrict__ outT, const float* __restrict__ outb,
    const float* __restrict__ lnw2, const float* __restrict__ lnb2,
    const short* __restrict__ m1T, const float* __restrict__ m1b,
    const short* __restrict__ m2T, const float* __restrict__ m2b) {
  __shared__ __align__(16) char smem[53248];
  short* hb  = (short*)smem;              // 17408 B: LN-out / q / P-scratch / attn-out
  short* kb  = (short*)(smem + 17408);    // 17408 B: k (intact thru attn); MLP G0
  short* vtb = (short*)(smem + 34816);    // 18432 B: V^T [feat128][key stride 72]; MLP G1
  float* red = (float*)(smem + 34816);    // 2048 B aliased at vtb base (LN phases only)

  const int tid = threadIdx.x;
  const int wid = tid >> 6;
  const int lane = tid & 63;
  const int l4 = lane & 15;
  const int quad = lane >> 4;
  const int n = blockIdx.x;

  short* xg = x + (size_t)n * 64 * 128;
  float xr[4][2][4];
  #pragma unroll
  for (int mt = 0; mt < 4; ++mt)
    #pragma unroll
    for (int nt = 0; nt < 2; ++nt)
      #pragma unroll
      for (int reg = 0; reg < 4; ++reg)
        xr[mt][nt][reg] = bf2f(xg[(mt*16 + quad*4 + reg)*128 + wid*32 + nt*16 + l4]);

  for (int l = 0; l < 2; ++l) {
    const float* g1    = lnw1 + l*128;   const float* bb1   = lnb1 + l*128;
    const short* qkvTl = qkvT + l*49152; const float* qkvbl = qkvb + l*384;
    const short* outTl = outT + l*16384; const float* outbl = outb + l*128;
    const float* g2    = lnw2 + l*128;   const float* bb2   = lnb2 + l*128;
    const short* m1Tl  = m1T + l*65536;  const float* m1bl  = m1b + l*512;
    const short* m2Tl  = m2T + l*65536;  const float* m2bl  = m2b + l*128;

    // guard red(=vtb) writes vs previous layer's MLP G1 reads
    __syncthreads();

    ln_sub(xr, g1, bb1, red, hb, wid, quad, l4);   // -> hb, trailing barrier

    // ---- QKV in two 32-row halves; unroll-1 fences cap register pressure ----
    #pragma unroll 1
    for (int hh = 0; hh < 2; ++hh) {
      s8v af[2][4];
      #pragma unroll
      for (int m2 = 0; m2 < 2; ++m2)
        #pragma unroll
        for (int k0 = 0; k0 < 4; ++k0)
          af[m2][k0] = *(const s8v*)(hb + ((hh*2 + m2)*16 + l4)*136 + k0*32 + quad*8);
      __syncthreads();   // all waves hold this half's h rows; safe to overwrite

      #pragma unroll 1
      for (int j = 0; j < 6; ++j) {
        int col = wid*96 + j*16 + l4;
        s8v bf[4];
        #pragma unroll
        for (int k0 = 0; k0 < 4; ++k0)
          bf[k0] = *(const s8v*)(qkvTl + col*128 + k0*32 + quad*8);
        float bias = qkvbl[col];
        f4v acc[2];
        #pragma unroll
        for (int m2 = 0; m2 < 2; ++m2) { f4v bb = {bias,bias,bias,bias}; acc[m2] = bb; }
        #pragma unroll
        for (int k0 = 0; k0 < 4; ++k0)
          #pragma unroll
          for (int m2 = 0; m2 < 2; ++m2)
            acc[m2] = MFMA16(af[m2][k0], bf[k0], acc[m2]);
        if (col < 128) {
          #pragma unroll
          for (int m2 = 0; m2 < 2; ++m2)
            #pragma unroll
            for (int reg = 0; reg < 4; ++reg)
              hb[((hh*2+m2)*16 + quad*4 + reg)*136 + col] = (short)f2bf(acc[m2][reg] * ATT_SCALE);
        } else if (col < 256) {
          int c = col - 128;
          #pragma unroll
          for (int m2 = 0; m2 < 2; ++m2)
            #pragma unroll
            for (int reg = 0; reg < 4; ++reg)
              kb[((hh*2+m2)*16 + quad*4 + reg)*136 + c] = (short)f2bf(acc[m2][reg]);
        } else {
          int c = col - 256;
          #pragma unroll
          for (int m2 = 0; m2 < 2; ++m2)
            #pragma unroll
            for (int reg = 0; reg < 4; ++reg)
              vtb[c*72 + (hh*2+m2)*16 + quad*4 + reg] = (short)f2bf(acc[m2][reg]);
        }
      }
    }
    __syncthreads();

    // ---- attention: wave = head; zero internal barriers; two query-halves.
    // P-scratch lives in hb (own q cols, rows of current hh); kb stays intact
    // so bk reloads per hh, freeing 16 arch regs during softmax.
    {
      const int h = wid;
      float rv[4];
      #pragma unroll
      for (int n2 = 0; n2 < 4; ++n2) rv[n2] = rm[n*64 + n2*16 + l4];

      #pragma unroll 1
      for (int hh = 0; hh < 2; ++hh) {
        s8v aq[2];
        #pragma unroll
        for (int m2 = 0; m2 < 2; ++m2)
          aq[m2] = *(const s8v*)(hb + ((hh*2+m2)*16 + l4)*136 + h*32 + quad*8);
        s8v bk[4];
        #pragma unroll
        for (int n2 = 0; n2 < 4; ++n2)
          bk[n2] = *(const s8v*)(kb + (n2*16 + l4)*136 + h*32 + quad*8);
        f4v S[2][4];
        #pragma unroll
        for (int m2 = 0; m2 < 2; ++m2)
          #pragma unroll
          for (int n2 = 0; n2 < 4; ++n2) {
            f4v zz = {0.f,0.f,0.f,0.f};
            S[m2][n2] = MFMA16(aq[m2], bk[n2], zz);
          }

        #pragma unroll
        for (int m2 = 0; m2 < 2; ++m2)
          #pragma unroll
          for (int reg = 0; reg < 4; ++reg) {
            float mx = fmaxf(fmaxf(S[m2][0][reg], S[m2][1][reg]),
                             fmaxf(S[m2][2][reg], S[m2][3][reg]));
            mx = fmaxf(mx, __shfl_xor(mx, 1));
            mx = fmaxf(mx, __shfl_xor(mx, 2));
            mx = fmaxf(mx, __shfl_xor(mx, 4));
            mx = fmaxf(mx, __shfl_xor(mx, 8));
            float E = 0.f, W = 0.f;
            #pragma unroll
            for (int n2 = 0; n2 < 4; ++n2) {
              float e = __expf(S[m2][n2][reg] - mx);
              E += e; W += e * rv[n2];
              S[m2][n2][reg] = e * rv[n2];
            }
            E += __shfl_xor(E, 1); E += __shfl_xor(E, 2);
            E += __shfl_xor(E, 4); E += __shfl_xor(E, 8);
            W += __shfl_xor(W, 1); W += __shfl_xor(W, 2);
            W += __shfl_xor(W, 4); W += __shfl_xor(W, 8);
            float inv = __builtin_amdgcn_rcpf(W + 1e-9f * E);
            #pragma unroll
            for (int n2 = 0; n2 < 4; ++n2) S[m2][n2][reg] *= inv;
          }

        // PV in 32-key chunks; P transposed through own hb region (q consumed)
        f4v o[2][2];
        #pragma unroll
        for (int m2 = 0; m2 < 2; ++m2)
          #pragma unroll
          for (int nt = 0; nt < 2; ++nt) { f4v zz = {0.f,0.f,0.f,0.f}; o[m2][nt] = zz; }
        #pragma unroll
        for (int c = 0; c < 2; ++c) {
          #pragma unroll
          for (int m2 = 0; m2 < 2; ++m2)
            #pragma unroll
            for (int n2 = 0; n2 < 2; ++n2)
              #pragma unroll
              for (int reg = 0; reg < 4; ++reg)
                hb[((hh*2+m2)*16 + quad*4 + reg)*136 + h*32 + n2*16 + l4] =
                    (short)f2bf(S[m2][2*c + n2][reg]);
          s8v ap[2];
          #pragma unroll
          for (int m2 = 0; m2 < 2; ++m2)
            ap[m2] = *(const s8v*)(hb + ((hh*2+m2)*16 + l4)*136 + h*32 + quad*8);
          #pragma unroll
          for (int nt = 0; nt < 2; ++nt) {
            s8v bv = *(const s8v*)(vtb + (h*32 + nt*16 + l4)*72 + c*32 + quad*8);
            #pragma unroll
            for (int m2 = 0; m2 < 2; ++m2)
              o[m2][nt] = MFMA16(ap[m2], bv, o[m2][nt]);
          }
        }
        #pragma unroll
        for (int m2 = 0; m2 < 2; ++m2)
          #pragma unroll
          for (int nt = 0; nt < 2; ++nt)
            #pragma unroll
            for (int reg = 0; reg < 4; ++reg)
              hb[((hh*2+m2)*16 + quad*4 + reg)*136 + h*32 + nt*16 + l4] =
                  (short)f2bf(o[m2][nt][reg]);
      }
    }
    __syncthreads();

    // ---- output proj + residual (xr-indexed: keep unrolled) ----
    #pragma unroll
    for (int hh = 0; hh < 2; ++hh) {
      s8v ao[2][4];
      #pragma unroll
      for (int m2 = 0; m2 < 2; ++m2)
        #pragma unroll
        for (int k0 = 0; k0 < 4; ++k0)
          ao[m2][k0] = *(const s8v*)(hb + ((hh*2+m2)*16 + l4)*136 + k0*32 + quad*8);
      #pragma unroll
      for (int nt = 0; nt < 2; ++nt) {
        int c = wid*32 + nt*16 + l4;
        s8v bo[4];
        #pragma unroll
        for (int k0 = 0; k0 < 4; ++k0)
          bo[k0] = *(const s8v*)(outTl + c*128 + k0*32 + quad*8);
        float bias = outbl[c];
        #pragma unroll
        for (int m2 = 0; m2 < 2; ++m2) {
          int mt = hh*2 + m2;
          f4v a2 = {xr[mt][nt][0] + bias, xr[mt][nt][1] + bias,
                    xr[mt][nt][2] + bias, xr[mt][nt][3] + bias};
          #pragma unroll
          for (int k0 = 0; k0 < 4; ++k0)
            a2 = MFMA16(ao[m2][k0], bo[k0], a2);
          #pragma unroll
          for (int reg = 0; reg < 4; ++reg)
            xr[mt][nt][reg] = a2[reg];
        }
      }
    }

    ln_sub(xr, g2, bb2, red, hb, wid, quad, l4);   // LN2 -> hb

    // ---- MLP: weights loaded inside nt loops to cap arch pressure ----
    #pragma unroll 1
    for (int cc = 0; cc < 4; ++cc) {
      short* G = (cc & 1) ? vtb : kb;
      #pragma unroll 1
      for (int hh = 0; hh < 2; ++hh) {
        s8v afm[2][4];
        #pragma unroll
        for (int m2 = 0; m2 < 2; ++m2)
          #pragma unroll
          for (int k0 = 0; k0 < 4; ++k0)
            afm[m2][k0] = *(const s8v*)(hb + ((hh*2+m2)*16 + l4)*136 + k0*32 + quad*8);
        #pragma unroll
        for (int nt = 0; nt < 2; ++nt) {
          int jc = cc*128 + wid*32 + nt*16 + l4;
          s8v bm[4];
          #pragma unroll
          for (int k0 = 0; k0 < 4; ++k0)
            bm[k0] = *(const s8v*)(m1Tl + jc*128 + k0*32 + quad*8);
          float bias = m1bl[jc];
          #pragma unroll
          for (int m2 = 0; m2 < 2; ++m2) {
            f4v a2 = {bias, bias, bias, bias};
            #pragma unroll
            for (int k0 = 0; k0 < 4; ++k0)
              a2 = MFMA16(afm[m2][k0], bm[k0], a2);
            #pragma unroll
            for (int reg = 0; reg < 4; ++reg) {
              // gelu(v) = v * sigmoid(2*sqrt(2/pi)*(v + 0.044715 v^3))
              float v = a2[reg];
              float t = v * v;
              float u = fmaf(0.044715f, t, 1.0f);
              float w = v * u;
              float e = __expf(NGC2 * w);
              float gl = v * __builtin_amdgcn_rcpf(e + 1.0f);
              G[((hh*2+m2)*16 + quad*4 + reg)*136 + wid*32 + nt*16 + l4] = (short)f2bf(gl);
            }
          }
        }
      }
      __syncthreads();
      #pragma unroll
      for (int hh = 0; hh < 2; ++hh) {
        s8v at4[2][4];
        #pragma unroll
        for (int m2 = 0; m2 < 2; ++m2)
          #pragma unroll
          for (int k0 = 0; k0 < 4; ++k0)
            at4[m2][k0] = *(const s8v*)(G + ((hh*2+m2)*16 + l4)*136 + k0*32 + quad*8);
        #pragma unroll
        for (int nt = 0; nt < 2; ++nt) {
          int c = wid*32 + nt*16 + l4;
          s8v b2f[4];
          #pragma unroll
          for (int k0 = 0; k0 < 4; ++k0)
            b2f[k0] = *(const s8v*)(m2Tl + c*512 + cc*128 + k0*32 + quad*8);
          #pragma unroll
          for (int m2 = 0; m2 < 2; ++m2) {
            int mt = hh*2 + m2;
            f4v a2 = {xr[mt][nt][0], xr[mt][nt][1], xr[mt][nt][2], xr[mt][nt][3]};
            #pragma unroll
            for (int k0 = 0; k0 < 4; ++k0)
              a2 = MFMA16(at4[m2][k0], b2f[k0], a2);
            #pragma unroll
            for (int reg = 0; reg < 4; ++reg)
              xr[mt][nt][reg] = a2[reg];
          }
        }
      }
    }
    #pragma unroll
    for (int nt = 0; nt < 2; ++nt) {
      float b = m2bl[wid*32 + nt*16 + l4];
      #pragma unroll
      for (int mt = 0; mt < 4; ++mt)
        #pragma unroll
        for (int reg = 0; reg < 4; ++reg)
          xr[mt][nt][reg] += b;
    }
  }

  #pragma unroll
  for (int mt = 0; mt < 4; ++mt)
    #pragma unroll
    for (int nt = 0; nt < 2; ++nt)
      #pragma unroll
      for (int reg = 0; reg < 4; ++reg)
        xg[(mt*16 + quad*4 + reg)*128 + wid*32 + nt*16 + l4] = (short)f2bf(xr[mt][nt][reg]);
}

// ---------------- gather + GNN linear (bf16 in/out) ----------------
__global__ __launch_bounds__(256) void k_gnn(
    const short* __restrict__ feat, const int* __restrict__ nef,
    const int* __restrict__ corr, const int* __restrict__ centers,
    const int* __restrict__ nef2, const short* __restrict__ gnnT,
    short* __restrict__ out) {
  __shared__ __align__(16) short Ab[64 * 264];
  int n = blockIdx.x, t = threadIdx.x;
  int wid = t >> 6, lane = t & 63, l4 = lane & 15, quad = lane >> 4;
  int j = t >> 2, qq = t & 3;
  int e  = iclamp(nef[n*64 + j], 0, N_EDGE - 1);
  int ce = iclamp(corr[e], 0, N_EDGE - 1);
  size_t r1 = ((size_t)iclamp(centers[e],  0, N_NODES-1) * 64 + iclamp(nef2[e],  0, 63)) * 128;
  size_t r2 = ((size_t)iclamp(centers[ce], 0, N_NODES-1) * 64 + iclamp(nef2[ce], 0, 63)) * 128;
  {
    const s8v* p1 = (const s8v*)(feat + r1 + qq*32);
    const s8v* p2 = (const s8v*)(feat + r2 + qq*32);
    #pragma unroll
    for (int ii = 0; ii < 4; ++ii) {
      *(s8v*)(Ab + j*264 + qq*32 + ii*8)       = p1[ii];
      *(s8v*)(Ab + j*264 + 128 + qq*32 + ii*8) = p2[ii];
    }
  }
  __syncthreads();
  f4v acc[4][2];
  #pragma unroll
  for (int mt = 0; mt < 4; ++mt)
    #pragma unroll
    for (int nt = 0; nt < 2; ++nt) { f4v zz = {0.f,0.f,0.f,0.f}; acc[mt][nt] = zz; }
  #pragma unroll
  for (int k0 = 0; k0 < 8; ++k0) {
    s8v a[4];
    #pragma unroll
    for (int mt = 0; mt < 4; ++mt)
      a[mt] = *(const s8v*)(Ab + (mt*16 + l4)*264 + k0*32 + quad*8);
    #pragma unroll
    for (int nt = 0; nt < 2; ++nt) {
      s8v b = *(const s8v*)(gnnT + (wid*32 + nt*16 + l4)*256 + k0*32 + quad*8);
      #pragma unroll
      for (int mt = 0; mt < 4; ++mt)
        acc[mt][nt] = MFMA16(a[mt], b, acc[mt][nt]);
    }
  }
  #pragma unroll
  for (int mt = 0; mt < 4; ++mt)
    #pragma unroll
    for (int nt = 0; nt < 2; ++nt)
      #pragma unroll
      for (int reg = 0; reg < 4; ++reg)
        out[((size_t)n*64 + mt*16 + quad*4 + reg)*128 + wid*32 + nt*16 + l4] =
            (short)f2bf(acc[mt][nt][reg]);
}

// ---------------- final masked sum + head ----------------
__global__ __launch_bounds__(256) void k_final(
    const short* __restrict__ feat, const short* __restrict__ buf2,
    const float* __restrict__ rm, const float* __restrict__ lastw,
    const float* __restrict__ compw, const int* __restrict__ species,
    float* __restrict__ out) {
  __shared__ float part[4];
  int n = blockIdx.x, t = threadIdx.x;
  int wid = t >> 6, lane = t & 63;
  int j = t >> 2, qq = t & 3;
  size_t base = ((size_t)n*64 + j)*128 + qq*32;
  float s = 0.f;
  #pragma unroll
  for (int i = 0; i < 32; ++i)
    s += (bf2f(feat[base + i]) + bf2f(buf2[base + i])) * lastw[qq*32 + i];
  s += __shfl_xor(s, 1);
  s += __shfl_xor(s, 2);
  float v = (qq == 0) ? s * rm[n*64 + j] : 0.f;
  v += __shfl_xor(v, 4);  v += __shfl_xor(v, 8);
  v += __shfl_xor(v, 16); v += __shfl_xor(v, 32);
  if (lane == 0) part[wid] = v;
  __syncthreads();
  if (t == 0) out[n] = part[0] + part[1] + part[2] + part[3]
                       + compw[iclamp(species[n], 0, 3)];
}

// ---------------- host ----------------

extern "C" void kernel_launch(void* const* d_in, const int* in_sizes, int n_in,
                              void* d_out, int out_size, void* d_ws, size_t ws_size,
                              hipStream_t stream) {
  const float* ev      = (const float*)d_in[0];
  const float* cart    = (const float*)d_in[1];
  const float* cemb    = (const float*)d_in[2];
  const float* nemb    = (const float*)d_in[3];
  const float* comp    = (const float*)d_in[4];
  const float* gnnw    = (const float*)d_in[5];
  const float* lastw   = (const float*)d_in[6];
  const float* compw   = (const float*)d_in[7];
  const int*   species = (const int*)d_in[8];
  const int*   centers = (const int*)d_in[9];
  const int*   neighbors = (const int*)d_in[10];
  const int*   nef     = (const int*)d_in[11];
  /* d_in[12] = nef_mask: unused (masked slots are provably inert) */
  const int*   nef2    = (const int*)d_in[13];
  const int*   corr    = (const int*)d_in[14];

  // workspace layout (bytes)
  const size_t OFF_RM   = 0;           // 1,048,576
  const size_t OFF_FEAT = 1048576;     // 67,108,864 (bf16)
  const size_t OFF_BUF2 = 68157440;    // 67,108,864 (bf16)
  const size_t OFF_TABS = 135266304;   // 5,632
  const size_t OFF_WBF  = 135271936;   // 1,638,400
  const size_t NEED     = 136910336;
  if (ws_size < NEED) return;  // insufficient scratch: fail cleanly, not a fault

  char* ws = (char*)d_ws;
  float* rm   = (float*)(ws + OFF_RM);
  short* feat = (short*)(ws + OFF_FEAT);
  short* buf2 = (short*)(ws + OFF_BUF2);
  float* tabs = (float*)(ws + OFF_TABS);
  short* wbf  = (short*)(ws + OFF_WBF);

  short* t0q  = wbf + 0;       // 2x(384x128)
  short* t0o  = wbf + 98304;   // 2x(128x128)
  short* t0m1 = wbf + 131072;  // 2x(512x128)
  short* t0m2 = wbf + 262144;  // 2x(128x512)
  short* t1q  = wbf + 393216;
  short* t1o  = wbf + 491520;
  short* t1m1 = wbf + 524288;
  short* t1m2 = wbf + 655360;
  short* gnnT = wbf + 786432;  // 128x256

  hipMemsetAsync(rm, 0, 4096*64*sizeof(float), stream);

  k_tr<<<384, 256, 0, stream>>>((const float*)d_in[17], t0q,  2, 128, 384);
  k_tr<<<128, 256, 0, stream>>>((const float*)d_in[19], t0o,  2, 128, 128);
  k_tr<<<512, 256, 0, stream>>>((const float*)d_in[23], t0m1, 2, 128, 512);
  k_tr<<<512, 256, 0, stream>>>((const float*)d_in[25], t0m2, 2, 512, 128);
  k_tr<<<384, 256, 0, stream>>>((const float*)d_in[29], t1q,  2, 128, 384);
  k_tr<<<128, 256, 0, stream>>>((const float*)d_in[31], t1o,  2, 128, 128);
  k_tr<<<512, 256, 0, stream>>>((const float*)d_in[35], t1m1, 2, 128, 512);
  k_tr<<<512, 256, 0, stream>>>((const float*)d_in[37], t1m2, 2, 512, 128);
  k_tr<<<128, 256, 0, stream>>>(gnnw, gnnT, 1, 256, 128);
  k_tabs<<<6, 256, 0, stream>>>(cart, cemb, nemb, comp, tabs);
  k_rm<<<512, 256, 0, stream>>>(ev, centers, nef2, rm);
  k_enc<<<4096, 256, 0, stream>>>(ev, nef, centers, neighbors, species, tabs, feat);

  k_tf<<<4096, 256, 0, stream>>>(feat, rm,
      (const float*)d_in[15], (const float*)d_in[16], t0q, (const float*)d_in[18],
      t0o, (const float*)d_in[20], (const float*)d_in[21], (const float*)d_in[22],
      t0m1, (const float*)d_in[24], t0m2, (const float*)d_in[26]);

  k_gnn<<<4096, 256, 0, stream>>>(feat, nef, corr, centers, nef2, gnnT, buf2);

  k_tf<<<4096, 256, 0, stream>>>(buf2, rm,
      (const float*)d_in[27], (const float*)d_in[28], t1q, (const float*)d_in[30],
      t1o, (const float*)d_in[32], (const float*)d_in[33], (const float*)d_in[34],
      t1m1, (const float*)d_in[36], t1m2, (const float*)d_in[38]);

  k_final<<<4096, 256, 0, stream>>>(feat, buf2, rm, lastw, compw, species, (float*)d_out);
}